// Round 2
// baseline (75.502 us; speedup 1.0000x reference)
//
#include <hip/hip_runtime.h>

#define BB 64
#define NN 307
#define HH 64
#define DD 768
#define EE 2456
#define ET 2763           // EE + NN self loops
#define MM (BB*NN)        // 19648
#define DEGMAX 128
#define SEGCAP 48

// ---- ws layout (bytes) ----
#define XL_OFF   0u
#define XL_SZ    (MM*DD*2u)              // 30,179,328
#define XR_OFF   (XL_OFF + XL_SZ)
#define GSRC_OFF (XR_OFF + XL_SZ)        // [NN][DEGMAX] ints
#define GDEG_OFF (GSRC_OFF + NN*DEGMAX*4u)

typedef __attribute__((ext_vector_type(8))) short short8;
typedef __attribute__((ext_vector_type(4))) float f32x4;
typedef __attribute__((ext_vector_type(2))) float f32x2;
typedef __attribute__((ext_vector_type(4))) unsigned u32x4;
typedef __attribute__((ext_vector_type(2))) unsigned u32x2;

__device__ __forceinline__ unsigned short f2bf(float f){
  union{float f; unsigned u;} c; c.f=f;
  unsigned u=c.u;
  return (unsigned short)((u + 0x7fffu + ((u>>16)&1u))>>16);
}

// ---------- 1. fused MFMA bf16 GEMM (xl AND xr) + CSR, one dispatch -------
// grid (307, 6, 2): z=0 -> both GEMMs for tile (x,y); z=1 (y==0) -> CSR node x.
// (round-0 version: 1842 compute blocks = 7.2/CU, good balance)
__global__ __launch_bounds__(256) void k_gemm(
    const float* __restrict__ z,
    const float* __restrict__ Wl, const float* __restrict__ bl,
    const float* __restrict__ Wr, const float* __restrict__ br,
    const int* __restrict__ r1, const int* __restrict__ r2,
    int* __restrict__ gdeg, int* __restrict__ gsrc,
    unsigned short* __restrict__ xl, unsigned short* __restrict__ xr)
{
  __shared__ unsigned short sBTl[128][72];  // Wl^T [col][k], padded (18 KB)
  __shared__ unsigned short sBTr[128][72];  // Wr^T [col][k], padded (18 KB)
  __shared__ unsigned short sC[64][136];    // epilogue staging, padded (17 KB)
  __shared__ int sseg[4][SEGCAP];
  __shared__ int scnt[4];

  const int tid = threadIdx.x;
  const int lane = tid & 63, wv = tid >> 6;

  if (blockIdx.z == 1){
    // ---- CSR: 4-wave segmented ballot scan for node n = blockIdx.x ----
    if (blockIdx.y != 0) return;
    const int n = blockIdx.x;
    const int W = (ET + 3) / 4;                 // 691
    const int e0 = wv * W;
    const int e1 = (e0 + W < ET) ? e0 + W : ET;
    int cnt = 0;
    for (int base = e0; base < e1; base += 64){
      int e = base + lane;
      int d = -1, s = 0;
      if (e < e1){
        if (e < EE){ d = r2[e]; s = r1[e]; }
        else       { d = e - EE; s = d; }
      }
      bool hit = (d == n);
      unsigned long long mb = __ballot(hit);
      if (hit){
        int pos = cnt + (int)__popcll(mb & ((1ull << lane) - 1ull));
        if (pos < SEGCAP) sseg[wv][pos] = s;
      }
      cnt += (int)__popcll(mb);
    }
    if (lane == 0) scnt[wv] = (cnt < SEGCAP) ? cnt : SEGCAP;
    __syncthreads();
    int c0 = scnt[0], c1 = scnt[1], c2 = scnt[2], c3 = scnt[3];
    int off = (wv > 0 ? c0 : 0) + (wv > 1 ? c1 : 0) + (wv > 2 ? c2 : 0);
    int cw = scnt[wv];
    int deg = c0 + c1 + c2 + c3;
    if (lane < cw && off + lane < DEGMAX) gsrc[n*DEGMAX + off + lane] = sseg[wv][lane];
    if (tid == 0) gdeg[n] = (deg < DEGMAX) ? deg : DEGMAX;
    return;
  }

  const int m0 = blockIdx.x*64, n0 = blockIdx.y*128;

  // stage BOTH W^T tiles (f32 -> bf16), coalesced
  #pragma unroll
  for (int it=0; it<32; it++){
    int idx = it*256 + tid;
    int k = idx >> 7, c = idx & 127;
    sBTl[c][k] = f2bf(Wl[(size_t)k*DD + n0 + c]);
    sBTr[c][k] = f2bf(Wr[(size_t)k*DD + n0 + c]);
  }

  // shared A fragments (one z read serves both GEMMs)
  const int arow = m0 + wv*16 + (lane & 15);
  const int kp   = (lane >> 4) * 8;
  const float* pz = z + (size_t)arow*HH + kp;
  float4 za0 = *(const float4*)(pz);
  float4 za1 = *(const float4*)(pz + 4);
  float4 zb0 = *(const float4*)(pz + 32);
  float4 zb1 = *(const float4*)(pz + 36);
  short8 a0, a1;
  a0[0]=(short)f2bf(za0.x); a0[1]=(short)f2bf(za0.y); a0[2]=(short)f2bf(za0.z); a0[3]=(short)f2bf(za0.w);
  a0[4]=(short)f2bf(za1.x); a0[5]=(short)f2bf(za1.y); a0[6]=(short)f2bf(za1.z); a0[7]=(short)f2bf(za1.w);
  a1[0]=(short)f2bf(zb0.x); a1[1]=(short)f2bf(zb0.y); a1[2]=(short)f2bf(zb0.z); a1[3]=(short)f2bf(zb0.w);
  a1[4]=(short)f2bf(zb1.x); a1[5]=(short)f2bf(zb1.y); a1[6]=(short)f2bf(zb1.z); a1[7]=(short)f2bf(zb1.w);
  __syncthreads();

  const int bcol = lane & 15;
  f32x4 accl[8], accr[8];
  #pragma unroll
  for (int cb=0; cb<8; cb++){
    accl[cb][0]=0.f; accl[cb][1]=0.f; accl[cb][2]=0.f; accl[cb][3]=0.f;
    accr[cb][0]=0.f; accr[cb][1]=0.f; accr[cb][2]=0.f; accr[cb][3]=0.f;
  }

  #pragma unroll
  for (int cb=0; cb<8; cb++){
    short8 b0l = *(const short8*)&sBTl[cb*16 + bcol][kp];
    short8 b1l = *(const short8*)&sBTl[cb*16 + bcol][32 + kp];
    accl[cb] = __builtin_amdgcn_mfma_f32_16x16x32_bf16(a0, b0l, accl[cb], 0, 0, 0);
    accl[cb] = __builtin_amdgcn_mfma_f32_16x16x32_bf16(a1, b1l, accl[cb], 0, 0, 0);
    short8 b0r = *(const short8*)&sBTr[cb*16 + bcol][kp];
    short8 b1r = *(const short8*)&sBTr[cb*16 + bcol][32 + kp];
    accr[cb] = __builtin_amdgcn_mfma_f32_16x16x32_bf16(a0, b0r, accr[cb], 0, 0, 0);
    accr[cb] = __builtin_amdgcn_mfma_f32_16x16x32_bf16(a1, b1r, accr[cb], 0, 0, 0);
  }

  // epilogue xl
  #pragma unroll
  for (int cb=0; cb<8; cb++){
    int cc = cb*16 + bcol;
    float bb = bl[n0 + cc];
    #pragma unroll
    for (int r=0; r<4; r++){
      int rr = wv*16 + (lane>>4)*4 + r;
      sC[rr][cc] = f2bf(accl[cb][r] + bb);
    }
  }
  __syncthreads();
  #pragma unroll
  for (int it=0; it<4; it++){
    int idx = it*256 + tid;
    int rr = idx >> 4;
    int c8 = (idx & 15) * 8;
    uint4 v = *(const uint4*)&sC[rr][c8];
    *(uint4*)&xl[(size_t)(m0+rr)*DD + n0 + c8] = v;
  }
  __syncthreads();
  // epilogue xr
  #pragma unroll
  for (int cb=0; cb<8; cb++){
    int cc = cb*16 + bcol;
    float bb = br[n0 + cc];
    #pragma unroll
    for (int r=0; r<4; r++){
      int rr = wv*16 + (lane>>4)*4 + r;
      sC[rr][cc] = f2bf(accr[cb][r] + bb);
    }
  }
  __syncthreads();
  #pragma unroll
  for (int it=0; it<4; it++){
    int idx = it*256 + tid;
    int rr = idx >> 4;
    int c8 = (idx & 15) * 8;
    uint4 v = *(const uint4*)&sC[rr][c8];
    *(uint4*)&xr[(size_t)(m0+rr)*DD + n0 + c8] = v;
  }
}

// ---------- 2. fused score + fixed-shift-softmax + aggregation ------------
// grid (64, 77); 256 threads = 4 INDEPENDENT waves (no LDS/barriers).
//   wave -> (n = blockIdx.y*4 + wv, b = blockIdx.x); lane owns 12 d-elems.
// Forced VOP3P packed-f32 math via inline asm (v_pk_add/mul/fma_f32) --
// hipcc does not form these from ext_vector float2 arithmetic on its own.
// Fixed-shift softmax (p = exp2(sc - 8*log2e), shift-invariant, |sc|<~6);
// scalar readlane gather addressing (saddr loads); 4-edge interleaved groups,
// only the final partial group is masked.

#define BF_LO(u) __uint_as_float((u) << 16)
#define BF_HI(u) __uint_as_float((u) & 0xffff0000u)

__device__ __forceinline__ f32x2 pk_add(f32x2 a, f32x2 b){
  f32x2 d; asm("v_pk_add_f32 %0, %1, %2" : "=v"(d) : "v"(a), "v"(b)); return d;
}
__device__ __forceinline__ f32x2 pk_mul(f32x2 a, f32x2 b){
  f32x2 d; asm("v_pk_mul_f32 %0, %1, %2" : "=v"(d) : "v"(a), "v"(b)); return d;
}
__device__ __forceinline__ f32x2 pk_fma(f32x2 a, f32x2 b, f32x2 c){
  f32x2 d; asm("v_pk_fma_f32 %0, %1, %2, %3" : "=v"(d) : "v"(a), "v"(b), "v"(c)); return d;
}
__device__ __forceinline__ f32x2 bfup(unsigned u){
  f32x2 r; r.x = BF_LO(u); r.y = BF_HI(u); return r;
}

// all-lane 64-lane sum: 4 DPP row_ror (16-row sums) + swizzle xor-16 + shfl xor-32
template<int CTRL>
__device__ __forceinline__ float dpp_add_ror(float v){
  int x = __builtin_amdgcn_update_dpp(0, __float_as_int(v), CTRL, 0xf, 0xf, true);
  return v + __int_as_float(x);
}
__device__ __forceinline__ float redux64(float v){
  v = dpp_add_ror<0x121>(v);   // row_ror:1
  v = dpp_add_ror<0x122>(v);   // row_ror:2
  v = dpp_add_ror<0x124>(v);   // row_ror:4
  v = dpp_add_ror<0x128>(v);   // row_ror:8  -> 16-lane row sums
  int x = __builtin_amdgcn_ds_swizzle(__float_as_int(v), 0x401F); // xor 16
  v = v + __int_as_float(x);
  return v + __shfl_xor(v, 32);
}

#define LOAD6(DST, P) {                                           \
  u32x4 _u0 = *(const u32x4*)(P);                                 \
  u32x2 _u1 = *(const u32x2*)((P)+4);                             \
  DST[0]=_u0.x; DST[1]=_u0.y; DST[2]=_u0.z; DST[3]=_u0.w;         \
  DST[4]=_u1.x; DST[5]=_u1.y; }

// clamped edge pointer: scalar src id via v_readlane (uniform j) -> saddr load
#define EPTR(J) ({                                                \
  int _j = (J); int _jc = _j < degm1 ? _j : degm1;                \
  int _s = __builtin_amdgcn_readlane((_jc & 64) ? sv1 : sv0, _jc & 63); \
  (const unsigned*)(xlb + (size_t)_s*DD) + du; })

#define MKH(H, U) {                                               \
  _Pragma("unroll")                                               \
  for (int _t=0;_t<6;_t++) H[_t] = pk_add(bfup(U[_t]), xrf2[_t]); }

#define SCORE(SC2, H) {                                           \
  _Pragma("unroll")                                               \
  for (int _t=0;_t<6;_t++){                                       \
    f32x2 _g = pk_mul(H[_t], c02);                                \
    f32x2 _l;                                                     \
    _l.x = fmaxf(H[_t].x, _g.x);                                  \
    _l.y = fmaxf(H[_t].y, _g.y);                                  \
    SC2 = pk_fma(_l, attv2[_t], SC2); } }

#define ACCH(PV, H) {                                             \
  _Pragma("unroll")                                               \
  for (int _t=0;_t<6;_t++) acc2[_t] = pk_fma(H[_t], PV, acc2[_t]); }

#define GROUP4(MASKED) {                                          \
  f32x2 hA[6],hB[6],hC[6],hD[6];                                  \
  MKH(hA,uA); MKH(hB,uB); MKH(hC,uC); MKH(hD,uD);                 \
  if (i + 4 < deg){      /* uniform branch: prefetch next group */\
    LOAD6(uA, EPTR(i+4)); LOAD6(uB, EPTR(i+5));                   \
    LOAD6(uC, EPTR(i+6)); LOAD6(uD, EPTR(i+7));                   \
  }                                                               \
  f32x2 sA2={0.f,0.f}, sB2={0.f,0.f}, sC2={0.f,0.f}, sD2={0.f,0.f};\
  SCORE(sA2,hA); SCORE(sB2,hB); SCORE(sC2,hC); SCORE(sD2,hD);     \
  float scA = redux64(sA2.x + sA2.y);                             \
  float scB = redux64(sB2.x + sB2.y);                             \
  float scC = redux64(sC2.x + sC2.y);                             \
  float scD = redux64(sD2.x + sD2.y);                             \
  float p0 = __builtin_amdgcn_exp2f(scA - C2);                    \
  float p1 = __builtin_amdgcn_exp2f(scB - C2);                    \
  float p2 = __builtin_amdgcn_exp2f(scC - C2);                    \
  float p3 = __builtin_amdgcn_exp2f(scD - C2);                    \
  if (MASKED){                                                    \
    p1 = (i+1 < deg) ? p1 : 0.f;                                  \
    p2 = (i+2 < deg) ? p2 : 0.f;                                  \
    p3 = (i+3 < deg) ? p3 : 0.f;                                  \
  }                                                               \
  ssum += (p0 + p1) + (p2 + p3);                                  \
  f32x2 pv;                                                       \
  pv.x = p0; pv.y = p0; ACCH(pv, hA);                             \
  pv.x = p1; pv.y = p1; ACCH(pv, hB);                             \
  pv.x = p2; pv.y = p2; ACCH(pv, hC);                             \
  pv.x = p3; pv.y = p3; ACCH(pv, hD);                             \
}

__global__ __launch_bounds__(256) void k_fusedf(
    const unsigned short* __restrict__ xl, const unsigned short* __restrict__ xr,
    const int* __restrict__ gdeg, const int* __restrict__ gsrc,
    const float* __restrict__ att, const float* __restrict__ bias,
    float* __restrict__ out)
{
  const int b = blockIdx.x;
  const int wv = threadIdx.x >> 6;
  const int nv = blockIdx.y*4 + wv;
  if (nv >= NN) return;                    // no barriers/LDS -> safe
  const int n = __builtin_amdgcn_readfirstlane(nv);   // force SGPR addressing
  const int lane = threadIdx.x & 63;
  const int du = lane * 6;           // uint (2-elem) offset within the 768-row

  // src list -> 2 VGPRs (coalesced); per-edge broadcast via v_readlane
  int sv0 = gsrc[n*DEGMAX + lane];
  int sv1 = gsrc[n*DEGMAX + 64 + lane];
  const int deg = __builtin_amdgcn_readfirstlane(gdeg[n]);  // >= 1 (self loop)
  const int degm1 = deg - 1;

  f32x2 attv2[6], xrf2[6], acc2[6];
  f32x2 c02; c02.x = 0.2f; c02.y = 0.2f;
  {
    const f32x2* pa2 = (const f32x2*)(att + du*2);
    #pragma unroll
    for (int t=0;t<6;t++) attv2[t] = pa2[t] * 1.4426950408889634f; // fold log2e
    // xr row: one-shot read, non-temporal (don't evict xl gather set)
    const unsigned* px = (const unsigned*)(xr + ((size_t)b*NN + n)*DD) + du;
    u32x4 x0 = __builtin_nontemporal_load((const u32x4*)px);
    u32x2 x1 = __builtin_nontemporal_load((const u32x2*)(px+4));
    unsigned xx[6] = {x0.x, x0.y, x0.z, x0.w, x1.x, x1.y};
    #pragma unroll
    for (int t=0;t<6;t++){
      xrf2[t].x = BF_LO(xx[t]);
      xrf2[t].y = BF_HI(xx[t]);
    }
  }
  #pragma unroll
  for (int t=0;t<6;t++){ acc2[t].x = 0.f; acc2[t].y = 0.f; }

  const unsigned short* xlb = xl + (size_t)b*NN*DD;
  float ssum = 0.f;
  const float C2 = 11.5415603f;      // 8 * log2(e); softmax is shift-invariant

  // prologue: first group in flight (clamped; tail masked)
  unsigned uA[6], uB[6], uC[6], uD[6];
  LOAD6(uA, EPTR(0)); LOAD6(uB, EPTR(1)); LOAD6(uC, EPTR(2)); LOAD6(uD, EPTR(3));

  int i = 0;
  for (; i + 4 <= deg; i += 4) GROUP4(false)   // full groups, no masking
  if (i < deg) GROUP4(true)                    // tail 1..3, masked p

  // out = acc_h/ssum - xr + bias   (since sum p*xr = ssum*xr); nt stores
  const float inv = 1.f / ssum;
  float* po = out + ((size_t)b*NN + n)*DD + du*2;
  const f32x2* pb2 = (const f32x2*)(bias + du*2);
  #pragma unroll
  for (int t=0;t<6;t+=2){
    f32x2 oa = acc2[t]   * inv + (pb2[t]   - xrf2[t]);
    f32x2 ob = acc2[t+1] * inv + (pb2[t+1] - xrf2[t+1]);
    f32x4 o4; o4[0]=oa.x; o4[1]=oa.y; o4[2]=ob.x; o4[3]=ob.y;
    __builtin_nontemporal_store(o4, (f32x4*)(po + 2*t));
  }
}

extern "C" void kernel_launch(void* const* d_in, const int* in_sizes, int n_in,
                              void* d_out, int out_size, void* d_ws, size_t ws_size,
                              hipStream_t stream)
{
  const float* z   = (const float*)d_in[1];
  const int*   r1  = (const int*)  d_in[2];
  const int*   r2  = (const int*)  d_in[3];
  const float* Wl  = (const float*)d_in[4];
  const float* bl  = (const float*)d_in[5];
  const float* Wr  = (const float*)d_in[6];
  const float* br  = (const float*)d_in[7];
  const float* att = (const float*)d_in[8];
  const float* bias= (const float*)d_in[9];
  float* out = (float*)d_out;

  char* ws = (char*)d_ws;
  unsigned short* xl = (unsigned short*)(ws + XL_OFF);
  unsigned short* xr = (unsigned short*)(ws + XR_OFF);
  int* gsrc = (int*)(ws + GSRC_OFF);
  int* gdeg = (int*)(ws + GDEG_OFF);

  k_gemm<<<dim3(MM/64, DD/128, 2), 256, 0, stream>>>(z, Wl, bl, Wr, br,
                                                     r1, r2, gdeg, gsrc, xl, xr);
  k_fusedf<<<dim3(BB, (NN+3)/4), 256, 0, stream>>>(xl, xr, gdeg, gsrc, att, bias, out);
}

// Round 3
// 69.723 us; speedup vs baseline: 1.0829x; 1.0829x over previous
//
#include <hip/hip_runtime.h>

#define BB 64
#define NN 307
#define HH 64
#define DD 768
#define EE 2456
#define ET 2763           // EE + NN self loops
#define MM (BB*NN)        // 19648
#define DEGMAX 128
#define SEGCAP 48

// ---- ws layout (bytes) ----
#define XL_OFF   0u
#define XL_SZ    (MM*DD*2u)              // 30,179,328
#define XR_OFF   (XL_OFF + XL_SZ)
#define GSRC_OFF (XR_OFF + XL_SZ)        // [NN][DEGMAX] ints
#define GDEG_OFF (GSRC_OFF + NN*DEGMAX*4u)

typedef __attribute__((ext_vector_type(8))) _Float16 half8;
typedef __attribute__((ext_vector_type(2))) _Float16 h2;
typedef __attribute__((ext_vector_type(4))) float f32x4;
typedef __attribute__((ext_vector_type(2))) float f32x2;
typedef __attribute__((ext_vector_type(4))) unsigned u32x4;
typedef __attribute__((ext_vector_type(2))) unsigned u32x2;

#if defined(__has_builtin)
#if __has_builtin(__builtin_amdgcn_fdot2)
#define HAS_FDOT2 1
#endif
#endif

__device__ __forceinline__ unsigned short f2h(float f){
  union{_Float16 h; unsigned short u;} c; c.h = (_Float16)f; return c.u;
}
__device__ __forceinline__ h2 u2h(unsigned u){
  union{unsigned u; h2 h;} c; c.u = u; return c.h;
}

// ---------- 1. fused MFMA f16 GEMM (xl AND xr) + CSR, one dispatch -------
// grid (307, 6, 2): z=0 -> both GEMMs for tile (x,y); z=1 (y==0) -> CSR node x.
// (round-0 structure verbatim; bf16 -> f16: mfma_f32_16x16x32_f16, f2h cvt)
__global__ __launch_bounds__(256) void k_gemm(
    const float* __restrict__ z,
    const float* __restrict__ Wl, const float* __restrict__ bl,
    const float* __restrict__ Wr, const float* __restrict__ br,
    const int* __restrict__ r1, const int* __restrict__ r2,
    int* __restrict__ gdeg, int* __restrict__ gsrc,
    unsigned short* __restrict__ xl, unsigned short* __restrict__ xr)
{
  __shared__ unsigned short sBTl[128][72];  // Wl^T [col][k], padded (18 KB)
  __shared__ unsigned short sBTr[128][72];  // Wr^T [col][k], padded (18 KB)
  __shared__ unsigned short sC[64][136];    // epilogue staging, padded (17 KB)
  __shared__ int sseg[4][SEGCAP];
  __shared__ int scnt[4];

  const int tid = threadIdx.x;
  const int lane = tid & 63, wv = tid >> 6;

  if (blockIdx.z == 1){
    // ---- CSR: 4-wave segmented ballot scan for node n = blockIdx.x ----
    if (blockIdx.y != 0) return;
    const int n = blockIdx.x;
    const int W = (ET + 3) / 4;                 // 691
    const int e0 = wv * W;
    const int e1 = (e0 + W < ET) ? e0 + W : ET;
    int cnt = 0;
    for (int base = e0; base < e1; base += 64){
      int e = base + lane;
      int d = -1, s = 0;
      if (e < e1){
        if (e < EE){ d = r2[e]; s = r1[e]; }
        else       { d = e - EE; s = d; }
      }
      bool hit = (d == n);
      unsigned long long mb = __ballot(hit);
      if (hit){
        int pos = cnt + (int)__popcll(mb & ((1ull << lane) - 1ull));
        if (pos < SEGCAP) sseg[wv][pos] = s;
      }
      cnt += (int)__popcll(mb);
    }
    if (lane == 0) scnt[wv] = (cnt < SEGCAP) ? cnt : SEGCAP;
    __syncthreads();
    int c0 = scnt[0], c1 = scnt[1], c2 = scnt[2], c3 = scnt[3];
    int off = (wv > 0 ? c0 : 0) + (wv > 1 ? c1 : 0) + (wv > 2 ? c2 : 0);
    int cw = scnt[wv];
    int deg = c0 + c1 + c2 + c3;
    if (lane < cw && off + lane < DEGMAX) gsrc[n*DEGMAX + off + lane] = sseg[wv][lane];
    if (tid == 0) gdeg[n] = (deg < DEGMAX) ? deg : DEGMAX;
    return;
  }

  const int m0 = blockIdx.x*64, n0 = blockIdx.y*128;

  // stage BOTH W^T tiles (f32 -> f16), coalesced
  #pragma unroll
  for (int it=0; it<32; it++){
    int idx = it*256 + tid;
    int k = idx >> 7, c = idx & 127;
    sBTl[c][k] = f2h(Wl[(size_t)k*DD + n0 + c]);
    sBTr[c][k] = f2h(Wr[(size_t)k*DD + n0 + c]);
  }

  // shared A fragments (one z read serves both GEMMs)
  const int arow = m0 + wv*16 + (lane & 15);
  const int kp   = (lane >> 4) * 8;
  const float* pz = z + (size_t)arow*HH + kp;
  float4 za0 = *(const float4*)(pz);
  float4 za1 = *(const float4*)(pz + 4);
  float4 zb0 = *(const float4*)(pz + 32);
  float4 zb1 = *(const float4*)(pz + 36);
  half8 a0, a1;
  a0[0]=(_Float16)za0.x; a0[1]=(_Float16)za0.y; a0[2]=(_Float16)za0.z; a0[3]=(_Float16)za0.w;
  a0[4]=(_Float16)za1.x; a0[5]=(_Float16)za1.y; a0[6]=(_Float16)za1.z; a0[7]=(_Float16)za1.w;
  a1[0]=(_Float16)zb0.x; a1[1]=(_Float16)zb0.y; a1[2]=(_Float16)zb0.z; a1[3]=(_Float16)zb0.w;
  a1[4]=(_Float16)zb1.x; a1[5]=(_Float16)zb1.y; a1[6]=(_Float16)zb1.z; a1[7]=(_Float16)zb1.w;
  __syncthreads();

  const int bcol = lane & 15;
  f32x4 accl[8], accr[8];
  #pragma unroll
  for (int cb=0; cb<8; cb++){
    accl[cb][0]=0.f; accl[cb][1]=0.f; accl[cb][2]=0.f; accl[cb][3]=0.f;
    accr[cb][0]=0.f; accr[cb][1]=0.f; accr[cb][2]=0.f; accr[cb][3]=0.f;
  }

  #pragma unroll
  for (int cb=0; cb<8; cb++){
    half8 b0l = *(const half8*)&sBTl[cb*16 + bcol][kp];
    half8 b1l = *(const half8*)&sBTl[cb*16 + bcol][32 + kp];
    accl[cb] = __builtin_amdgcn_mfma_f32_16x16x32_f16(a0, b0l, accl[cb], 0, 0, 0);
    accl[cb] = __builtin_amdgcn_mfma_f32_16x16x32_f16(a1, b1l, accl[cb], 0, 0, 0);
    half8 b0r = *(const half8*)&sBTr[cb*16 + bcol][kp];
    half8 b1r = *(const half8*)&sBTr[cb*16 + bcol][32 + kp];
    accr[cb] = __builtin_amdgcn_mfma_f32_16x16x32_f16(a0, b0r, accr[cb], 0, 0, 0);
    accr[cb] = __builtin_amdgcn_mfma_f32_16x16x32_f16(a1, b1r, accr[cb], 0, 0, 0);
  }

  // epilogue xl
  #pragma unroll
  for (int cb=0; cb<8; cb++){
    int cc = cb*16 + bcol;
    float bb = bl[n0 + cc];
    #pragma unroll
    for (int r=0; r<4; r++){
      int rr = wv*16 + (lane>>4)*4 + r;
      sC[rr][cc] = f2h(accl[cb][r] + bb);
    }
  }
  __syncthreads();
  #pragma unroll
  for (int it=0; it<4; it++){
    int idx = it*256 + tid;
    int rr = idx >> 4;
    int c8 = (idx & 15) * 8;
    uint4 v = *(const uint4*)&sC[rr][c8];
    *(uint4*)&xl[(size_t)(m0+rr)*DD + n0 + c8] = v;
  }
  __syncthreads();
  // epilogue xr
  #pragma unroll
  for (int cb=0; cb<8; cb++){
    int cc = cb*16 + bcol;
    float bb = br[n0 + cc];
    #pragma unroll
    for (int r=0; r<4; r++){
      int rr = wv*16 + (lane>>4)*4 + r;
      sC[rr][cc] = f2h(accr[cb][r] + bb);
    }
  }
  __syncthreads();
  #pragma unroll
  for (int it=0; it<4; it++){
    int idx = it*256 + tid;
    int rr = idx >> 4;
    int c8 = (idx & 15) * 8;
    uint4 v = *(const uint4*)&sC[rr][c8];
    *(uint4*)&xr[(size_t)(m0+rr)*DD + n0 + c8] = v;
  }
}

// ---------- 2. fused score + fixed-shift-softmax + aggregation ------------
// grid (64, 77); 256 threads = 4 INDEPENDENT waves (no LDS/barriers).
//   wave -> (n = blockIdx.y*4 + wv, b = blockIdx.x); lane owns 12 d-elems.
// R0 loop skeleton verbatim (4-deep prefetch, peel; software-pipelineable).
// New: f16 packed math (v_pk_add/mul/max_f16 + v_dot2_f32_f16 per uint),
// fixed-shift softmax (exp2, no online max), scalar loop control + readlane
// edge addressing (saddr gathers), all-DPP reduction (no LDS-pipe ops).

template<int CTRL, int RM>
__device__ __forceinline__ float dpp_add(float v){
  int x = __builtin_amdgcn_update_dpp(0, __float_as_int(v), CTRL, RM, 0xf, true);
  return v + __int_as_float(x);
}
// 64-lane sum -> wave-uniform float (SGPR via readlane 63). All-VALU.
__device__ __forceinline__ float redux64s(float v){
  v = dpp_add<0x121,0xf>(v);   // row_ror:1
  v = dpp_add<0x122,0xf>(v);   // row_ror:2
  v = dpp_add<0x124,0xf>(v);   // row_ror:4
  v = dpp_add<0x128,0xf>(v);   // row_ror:8   -> every lane: own 16-row sum
  v = dpp_add<0x142,0xa>(v);   // row_bcast:15 -> row1 += r0, row3 += r2
  v = dpp_add<0x143,0x8>(v);   // row_bcast:31 -> row3 += (r0+r1)
  return __uint_as_float((unsigned)__builtin_amdgcn_readlane(__float_as_int(v), 63));
}

#define LOAD6(DST, P) {                                           \
  u32x4 _u0 = *(const u32x4*)(P);                                 \
  u32x2 _u1 = *(const u32x2*)((P)+4);                             \
  DST[0]=_u0.x; DST[1]=_u0.y; DST[2]=_u0.z; DST[3]=_u0.w;         \
  DST[4]=_u1.x; DST[5]=_u1.y; }

// scalar src id (I uniform, SGPR loop) -> saddr gather base
#define READS(I) __builtin_amdgcn_readlane((((I) & 64) ? sv1 : sv0), (I) & 63)
#define EADDR(I) ((const unsigned*)(xlb + (size_t)READS(I)*DD) + du)

#define MKH(H, U) {                                               \
  _Pragma("unroll")                                               \
  for (int _t=0;_t<6;_t++) H[_t] = u2h(U[_t]) + xrh[_t]; }        // v_pk_add_f16

#ifdef HAS_FDOT2
#define SCORE(S, H) {                                             \
  _Pragma("unroll")                                               \
  for (int _t=0;_t<6;_t++){                                       \
    h2 _l = __builtin_elementwise_max(H[_t], H[_t]*c02h);         \
    S = __builtin_amdgcn_fdot2(_l, atth[_t], S, false); } }
#else
#define SCORE(S, H) {                                             \
  _Pragma("unroll")                                               \
  for (int _t=0;_t<6;_t++){                                       \
    h2 _l = __builtin_elementwise_max(H[_t], H[_t]*c02h);         \
    S += (float)_l[0]*attf[2*_t] + (float)_l[1]*attf[2*_t+1]; } }
#endif

#define ACCH(P, H) {                                              \
  _Pragma("unroll")                                               \
  for (int _t=0;_t<6;_t++){                                       \
    acc2[_t].x += (P) * (float)H[_t][0];                          \
    acc2[_t].y += (P) * (float)H[_t][1]; } }

#define STEP2(U, V) {                                             \
  h2 hU[6], hV[6];                                                \
  MKH(hU, U); MKH(hV, V);                                         \
  float sU = 0.f, sV = 0.f;                                       \
  SCORE(sU, hU); SCORE(sV, hV);                                   \
  float scU = redux64s(sU);                                       \
  float scV = redux64s(sV);                                       \
  float pU = __builtin_amdgcn_exp2f(scU - C2);                    \
  float pV = __builtin_amdgcn_exp2f(scV - C2);                    \
  ssum += pU + pV;                                                \
  ACCH(pU, hU); ACCH(pV, hV); }

#define STEP1(U) {                                                \
  h2 hU[6];                                                       \
  MKH(hU, U);                                                     \
  float sU = 0.f;                                                 \
  SCORE(sU, hU);                                                  \
  float scU = redux64s(sU);                                       \
  float pU = __builtin_amdgcn_exp2f(scU - C2);                    \
  ssum += pU;                                                     \
  ACCH(pU, hU); }

__global__ __launch_bounds__(256) void k_fusedf(
    const unsigned short* __restrict__ xl, const unsigned short* __restrict__ xr,
    const int* __restrict__ gdeg, const int* __restrict__ gsrc,
    const float* __restrict__ att, const float* __restrict__ bias,
    float* __restrict__ out)
{
  const int b = blockIdx.x;
  const int wv = threadIdx.x >> 6;
  const int nv = blockIdx.y*4 + wv;
  if (nv >= NN) return;                    // no barriers/LDS -> safe
  const int n = __builtin_amdgcn_readfirstlane(nv);  // wave-uniform -> SGPR
  const int lane = threadIdx.x & 63;
  const int du = lane * 6;           // uint (2-elem) offset within the 768-row

  // src list -> 2 VGPRs (coalesced); per-edge broadcast via v_readlane
  int sv0 = gsrc[n*DEGMAX + lane];
  int sv1 = gsrc[n*DEGMAX + 64 + lane];
  const int deg = __builtin_amdgcn_readfirstlane(gdeg[n]);  // SGPR loop bound

  h2 atth[6], xrh[6];
  f32x2 acc2[6], xrf2[6];
  const h2 c02h = {(_Float16)0.2f, (_Float16)0.2f};
#ifndef HAS_FDOT2
  float attf[12];
#endif
  {
    const f32x2* pa2 = (const f32x2*)(att + du*2);
    #pragma unroll
    for (int t=0;t<6;t++){
      f32x2 a = pa2[t];
      atth[t][0] = (_Float16)(a.x * 1.4426950408889634f);  // fold log2e
      atth[t][1] = (_Float16)(a.y * 1.4426950408889634f);
#ifndef HAS_FDOT2
      attf[2*t]   = a.x * 1.4426950408889634f;
      attf[2*t+1] = a.y * 1.4426950408889634f;
#endif
    }
    // xr row: one-shot read, non-temporal (don't evict xl gather set)
    const unsigned* px = (const unsigned*)(xr + ((size_t)b*NN + n)*DD) + du;
    u32x4 x0 = __builtin_nontemporal_load((const u32x4*)px);
    u32x2 x1 = __builtin_nontemporal_load((const u32x2*)(px+4));
    unsigned xx[6] = {x0.x, x0.y, x0.z, x0.w, x1.x, x1.y};
    #pragma unroll
    for (int t=0;t<6;t++){
      xrh[t] = u2h(xx[t]);
      xrf2[t].x = (float)xrh[t][0];
      xrf2[t].y = (float)xrh[t][1];
    }
  }
  #pragma unroll
  for (int t=0;t<6;t++){ acc2[t].x = 0.f; acc2[t].y = 0.f; }

  const unsigned short* xlb = xl + (size_t)b*NN*DD;
  float ssum = 0.f;
  const float C2 = 11.5415603f;      // 8*log2(e); softmax is shift-invariant

  // ---- edge-pair loop, 4-deep prefetch, zero barriers (R0 skeleton) ----
  unsigned bA[6], bB[6], bC[6], bD[6];
  int i = 0;
  LOAD6(bA, EADDR(0));
  if (deg > 1) LOAD6(bB, EADDR(1));
  for (; i + 4 <= deg; ){
    LOAD6(bC, EADDR(i+2));
    LOAD6(bD, EADDR(i+3));
    STEP2(bA, bB);
    i += 4;
    if (i     < deg) LOAD6(bA, EADDR(i));
    if (i + 1 < deg) LOAD6(bB, EADDR(i+1));
    STEP2(bC, bD);
  }
  {
    int rem = deg - i;                    // 0..3; edges i,i+1 already in bA,bB
    if (rem >= 2){
      if (rem == 3) LOAD6(bC, EADDR(i+2));
      STEP2(bA, bB);
      if (rem == 3) STEP1(bC);
    } else if (rem == 1){
      STEP1(bA);
    }
  }

  // out = acc_h/ssum - xr + bias   (since sum p*xr = ssum*xr); nt stores
  const float inv = 1.f / ssum;
  float* po = out + ((size_t)b*NN + n)*DD + du*2;
  const f32x2* pb2 = (const f32x2*)(bias + du*2);
  #pragma unroll
  for (int t=0;t<6;t+=2){
    f32x2 oa = acc2[t]   * inv + (pb2[t]   - xrf2[t]);
    f32x2 ob = acc2[t+1] * inv + (pb2[t+1] - xrf2[t+1]);
    f32x4 o4; o4[0]=oa.x; o4[1]=oa.y; o4[2]=ob.x; o4[3]=ob.y;
    __builtin_nontemporal_store(o4, (f32x4*)(po + 2*t));
  }
}

extern "C" void kernel_launch(void* const* d_in, const int* in_sizes, int n_in,
                              void* d_out, int out_size, void* d_ws, size_t ws_size,
                              hipStream_t stream)
{
  const float* z   = (const float*)d_in[1];
  const int*   r1  = (const int*)  d_in[2];
  const int*   r2  = (const int*)  d_in[3];
  const float* Wl  = (const float*)d_in[4];
  const float* bl  = (const float*)d_in[5];
  const float* Wr  = (const float*)d_in[6];
  const float* br  = (const float*)d_in[7];
  const float* att = (const float*)d_in[8];
  const float* bias= (const float*)d_in[9];
  float* out = (float*)d_out;

  char* ws = (char*)d_ws;
  unsigned short* xl = (unsigned short*)(ws + XL_OFF);
  unsigned short* xr = (unsigned short*)(ws + XR_OFF);
  int* gsrc = (int*)(ws + GSRC_OFF);
  int* gdeg = (int*)(ws + GDEG_OFF);

  k_gemm<<<dim3(MM/64, DD/128, 2), 256, 0, stream>>>(z, Wl, bl, Wr, br,
                                                     r1, r2, gdeg, gsrc, xl, xr);
  k_fusedf<<<dim3(BB, (NN+3)/4), 256, 0, stream>>>(xl, xr, gdeg, gsrc, att, bias, out);
}

// Round 4
// 68.606 us; speedup vs baseline: 1.1005x; 1.0163x over previous
//
#include <hip/hip_runtime.h>

#define BB 64
#define NN 307
#define HH 64
#define DD 768
#define EE 2456
#define ET 2763           // EE + NN self loops
#define MM (BB*NN)        // 19648
#define DEGMAX 128
#define SEGCAP 48

// ---- ws layout (bytes) ----
#define XL_OFF   0u
#define XL_SZ    (MM*DD*2u)              // 30,179,328
#define XR_OFF   (XL_OFF + XL_SZ)
#define GSRC_OFF (XR_OFF + XL_SZ)        // [NN][DEGMAX] ints
#define GDEG_OFF (GSRC_OFF + NN*DEGMAX*4u)

typedef __attribute__((ext_vector_type(8))) _Float16 half8;
typedef __attribute__((ext_vector_type(2))) _Float16 h2;
typedef __attribute__((ext_vector_type(4))) float f32x4;
typedef __attribute__((ext_vector_type(2))) float f32x2;
typedef __attribute__((ext_vector_type(4))) unsigned u32x4;
typedef __attribute__((ext_vector_type(2))) unsigned u32x2;

#if defined(__has_builtin)
#if __has_builtin(__builtin_amdgcn_fdot2)
#define HAS_FDOT2 1
#endif
#endif

__device__ __forceinline__ unsigned short f2h(float f){
  union{_Float16 h; unsigned short u;} c; c.h = (_Float16)f; return c.u;
}
__device__ __forceinline__ h2 u2h(unsigned u){
  union{unsigned u; h2 h;} c; c.u = u; return c.h;
}

// ---------- 1. fused MFMA f16 GEMM (xl AND xr) + CSR, one dispatch -------
// grid (307, 6, 2): z=0 -> both GEMMs for tile (x,y); z=1 (y==0) -> CSR node x.
// (unchanged from round 3)
__global__ __launch_bounds__(256) void k_gemm(
    const float* __restrict__ z,
    const float* __restrict__ Wl, const float* __restrict__ bl,
    const float* __restrict__ Wr, const float* __restrict__ br,
    const int* __restrict__ r1, const int* __restrict__ r2,
    int* __restrict__ gdeg, int* __restrict__ gsrc,
    unsigned short* __restrict__ xl, unsigned short* __restrict__ xr)
{
  __shared__ unsigned short sBTl[128][72];  // Wl^T [col][k], padded (18 KB)
  __shared__ unsigned short sBTr[128][72];  // Wr^T [col][k], padded (18 KB)
  __shared__ unsigned short sC[64][136];    // epilogue staging, padded (17 KB)
  __shared__ int sseg[4][SEGCAP];
  __shared__ int scnt[4];

  const int tid = threadIdx.x;
  const int lane = tid & 63, wv = tid >> 6;

  if (blockIdx.z == 1){
    // ---- CSR: 4-wave segmented ballot scan for node n = blockIdx.x ----
    if (blockIdx.y != 0) return;
    const int n = blockIdx.x;
    const int W = (ET + 3) / 4;                 // 691
    const int e0 = wv * W;
    const int e1 = (e0 + W < ET) ? e0 + W : ET;
    int cnt = 0;
    for (int base = e0; base < e1; base += 64){
      int e = base + lane;
      int d = -1, s = 0;
      if (e < e1){
        if (e < EE){ d = r2[e]; s = r1[e]; }
        else       { d = e - EE; s = d; }
      }
      bool hit = (d == n);
      unsigned long long mb = __ballot(hit);
      if (hit){
        int pos = cnt + (int)__popcll(mb & ((1ull << lane) - 1ull));
        if (pos < SEGCAP) sseg[wv][pos] = s;
      }
      cnt += (int)__popcll(mb);
    }
    if (lane == 0) scnt[wv] = (cnt < SEGCAP) ? cnt : SEGCAP;
    __syncthreads();
    int c0 = scnt[0], c1 = scnt[1], c2 = scnt[2], c3 = scnt[3];
    int off = (wv > 0 ? c0 : 0) + (wv > 1 ? c1 : 0) + (wv > 2 ? c2 : 0);
    int cw = scnt[wv];
    int deg = c0 + c1 + c2 + c3;
    if (lane < cw && off + lane < DEGMAX) gsrc[n*DEGMAX + off + lane] = sseg[wv][lane];
    if (tid == 0) gdeg[n] = (deg < DEGMAX) ? deg : DEGMAX;
    return;
  }

  const int m0 = blockIdx.x*64, n0 = blockIdx.y*128;

  // stage BOTH W^T tiles (f32 -> f16), coalesced
  #pragma unroll
  for (int it=0; it<32; it++){
    int idx = it*256 + tid;
    int k = idx >> 7, c = idx & 127;
    sBTl[c][k] = f2h(Wl[(size_t)k*DD + n0 + c]);
    sBTr[c][k] = f2h(Wr[(size_t)k*DD + n0 + c]);
  }

  // shared A fragments (one z read serves both GEMMs)
  const int arow = m0 + wv*16 + (lane & 15);
  const int kp   = (lane >> 4) * 8;
  const float* pz = z + (size_t)arow*HH + kp;
  float4 za0 = *(const float4*)(pz);
  float4 za1 = *(const float4*)(pz + 4);
  float4 zb0 = *(const float4*)(pz + 32);
  float4 zb1 = *(const float4*)(pz + 36);
  half8 a0, a1;
  a0[0]=(_Float16)za0.x; a0[1]=(_Float16)za0.y; a0[2]=(_Float16)za0.z; a0[3]=(_Float16)za0.w;
  a0[4]=(_Float16)za1.x; a0[5]=(_Float16)za1.y; a0[6]=(_Float16)za1.z; a0[7]=(_Float16)za1.w;
  a1[0]=(_Float16)zb0.x; a1[1]=(_Float16)zb0.y; a1[2]=(_Float16)zb0.z; a1[3]=(_Float16)zb0.w;
  a1[4]=(_Float16)zb1.x; a1[5]=(_Float16)zb1.y; a1[6]=(_Float16)zb1.z; a1[7]=(_Float16)zb1.w;
  __syncthreads();

  const int bcol = lane & 15;
  f32x4 accl[8], accr[8];
  #pragma unroll
  for (int cb=0; cb<8; cb++){
    accl[cb][0]=0.f; accl[cb][1]=0.f; accl[cb][2]=0.f; accl[cb][3]=0.f;
    accr[cb][0]=0.f; accr[cb][1]=0.f; accr[cb][2]=0.f; accr[cb][3]=0.f;
  }

  #pragma unroll
  for (int cb=0; cb<8; cb++){
    half8 b0l = *(const half8*)&sBTl[cb*16 + bcol][kp];
    half8 b1l = *(const half8*)&sBTl[cb*16 + bcol][32 + kp];
    accl[cb] = __builtin_amdgcn_mfma_f32_16x16x32_f16(a0, b0l, accl[cb], 0, 0, 0);
    accl[cb] = __builtin_amdgcn_mfma_f32_16x16x32_f16(a1, b1l, accl[cb], 0, 0, 0);
    half8 b0r = *(const half8*)&sBTr[cb*16 + bcol][kp];
    half8 b1r = *(const half8*)&sBTr[cb*16 + bcol][32 + kp];
    accr[cb] = __builtin_amdgcn_mfma_f32_16x16x32_f16(a0, b0r, accr[cb], 0, 0, 0);
    accr[cb] = __builtin_amdgcn_mfma_f32_16x16x32_f16(a1, b1r, accr[cb], 0, 0, 0);
  }

  // epilogue xl
  #pragma unroll
  for (int cb=0; cb<8; cb++){
    int cc = cb*16 + bcol;
    float bb = bl[n0 + cc];
    #pragma unroll
    for (int r=0; r<4; r++){
      int rr = wv*16 + (lane>>4)*4 + r;
      sC[rr][cc] = f2h(accl[cb][r] + bb);
    }
  }
  __syncthreads();
  #pragma unroll
  for (int it=0; it<4; it++){
    int idx = it*256 + tid;
    int rr = idx >> 4;
    int c8 = (idx & 15) * 8;
    uint4 v = *(const uint4*)&sC[rr][c8];
    *(uint4*)&xl[(size_t)(m0+rr)*DD + n0 + c8] = v;
  }
  __syncthreads();
  // epilogue xr
  #pragma unroll
  for (int cb=0; cb<8; cb++){
    int cc = cb*16 + bcol;
    float bb = br[n0 + cc];
    #pragma unroll
    for (int r=0; r<4; r++){
      int rr = wv*16 + (lane>>4)*4 + r;
      sC[rr][cc] = f2h(accr[cb][r] + bb);
    }
  }
  __syncthreads();
  #pragma unroll
  for (int it=0; it<4; it++){
    int idx = it*256 + tid;
    int rr = idx >> 4;
    int c8 = (idx & 15) * 8;
    uint4 v = *(const uint4*)&sC[rr][c8];
    *(uint4*)&xr[(size_t)(m0+rr)*DD + n0 + c8] = v;
  }
}

// ---------- 2. fused score + fixed-shift-softmax + aggregation ------------
// grid (64, 77); 256 threads = 4 INDEPENDENT waves (no LDS/barriers).
//   wave -> (n = blockIdx.y*4 + wv, b = blockIdx.x); lane owns 12 d-elems.
// Round-4 change: 8-edge-deep software pipeline (16 vmem in flight).
//   avg deg ~9 -> the prologue issues essentially ALL of a node's gathers
//   up-front; their L2/L3/HBM latencies overlap into ~one exposure per wave.
//   In-loop reloads are issued 3 STEP2s (~6 edges) before use.
//   Out-of-range slots are clamped to the last valid src (branchless s_min;
//   duplicate same-row loads are L1 hits, values never consumed).
// Math identical to round 3 (f16 packed + dot2, fixed-shift exp2 softmax,
// all-DPP reduction, scalar readlane addressing -> saddr gathers).

template<int CTRL, int RM>
__device__ __forceinline__ float dpp_add(float v){
  int x = __builtin_amdgcn_update_dpp(0, __float_as_int(v), CTRL, RM, 0xf, true);
  return v + __int_as_float(x);
}
// 64-lane sum -> wave-uniform float (readlane 63). All-VALU, no LDS pipe.
__device__ __forceinline__ float redux64s(float v){
  v = dpp_add<0x121,0xf>(v);   // row_ror:1
  v = dpp_add<0x122,0xf>(v);   // row_ror:2
  v = dpp_add<0x124,0xf>(v);   // row_ror:4
  v = dpp_add<0x128,0xf>(v);   // row_ror:8   -> every lane: own 16-row sum
  v = dpp_add<0x142,0xa>(v);   // row_bcast:15 -> row1 += r0, row3 += r2
  v = dpp_add<0x143,0x8>(v);   // row_bcast:31 -> row3 += (r0+r1)
  return __uint_as_float((unsigned)__builtin_amdgcn_readlane(__float_as_int(v), 63));
}

#define LOAD6(DST, P) {                                           \
  u32x4 _u0 = *(const u32x4*)(P);                                 \
  u32x2 _u1 = *(const u32x2*)((P)+4);                             \
  DST[0]=_u0.x; DST[1]=_u0.y; DST[2]=_u0.z; DST[3]=_u0.w;         \
  DST[4]=_u1.x; DST[5]=_u1.y; }

// scalar src id (J uniform) -> saddr gather base; C-variant clamps to degm1
#define READS(J) __builtin_amdgcn_readlane((((J) & 64) ? sv1 : sv0), (J) & 63)
#define EADDR(J)  ((const unsigned*)(xlb + (size_t)READS(J)*DD) + du)
#define EADDRC(J) ({ int _q = (J); int _qc = _q < degm1 ? _q : degm1;  \
                     (const unsigned*)(xlb + (size_t)READS(_qc)*DD) + du; })

#define MKH(H, U) {                                               \
  _Pragma("unroll")                                               \
  for (int _t=0;_t<6;_t++) H[_t] = u2h(U[_t]) + xrh[_t]; }        // v_pk_add_f16

#ifdef HAS_FDOT2
#define SCORE(S, H) {                                             \
  _Pragma("unroll")                                               \
  for (int _t=0;_t<6;_t++){                                       \
    h2 _l = __builtin_elementwise_max(H[_t], H[_t]*c02h);         \
    S = __builtin_amdgcn_fdot2(_l, atth[_t], S, false); } }
#else
#define SCORE(S, H) {                                             \
  _Pragma("unroll")                                               \
  for (int _t=0;_t<6;_t++){                                       \
    h2 _l = __builtin_elementwise_max(H[_t], H[_t]*c02h);         \
    S += (float)_l[0]*attf[2*_t] + (float)_l[1]*attf[2*_t+1]; } }
#endif

#define ACCH(P, H) {                                              \
  _Pragma("unroll")                                               \
  for (int _t=0;_t<6;_t++){                                       \
    acc2[_t].x += (P) * (float)H[_t][0];                          \
    acc2[_t].y += (P) * (float)H[_t][1]; } }

#define STEP2(U, V) {                                             \
  h2 hU[6], hV[6];                                                \
  MKH(hU, U); MKH(hV, V);                                         \
  float sU = 0.f, sV = 0.f;                                       \
  SCORE(sU, hU); SCORE(sV, hV);                                   \
  float scU = redux64s(sU);                                       \
  float scV = redux64s(sV);                                       \
  float pU = __builtin_amdgcn_exp2f(scU - C2);                    \
  float pV = __builtin_amdgcn_exp2f(scV - C2);                    \
  ssum += pU + pV;                                                \
  ACCH(pU, hU); ACCH(pV, hV); }

#define STEP1(U) {                                                \
  h2 hU[6];                                                       \
  MKH(hU, U);                                                     \
  float sU = 0.f;                                                 \
  SCORE(sU, hU);                                                  \
  float scU = redux64s(sU);                                       \
  float pU = __builtin_amdgcn_exp2f(scU - C2);                    \
  ssum += pU;                                                     \
  ACCH(pU, hU); }

__global__ __launch_bounds__(256) void k_fusedf(
    const unsigned short* __restrict__ xl, const unsigned short* __restrict__ xr,
    const int* __restrict__ gdeg, const int* __restrict__ gsrc,
    const float* __restrict__ att, const float* __restrict__ bias,
    float* __restrict__ out)
{
  const int b = blockIdx.x;
  const int wv = threadIdx.x >> 6;
  const int nv = blockIdx.y*4 + wv;
  if (nv >= NN) return;                    // no barriers/LDS -> safe
  const int n = __builtin_amdgcn_readfirstlane(nv);  // wave-uniform -> SGPR
  const int lane = threadIdx.x & 63;
  const int du = lane * 6;           // uint (2-elem) offset within the 768-row

  // src list -> 2 VGPRs (coalesced); per-edge broadcast via v_readlane
  int sv0 = gsrc[n*DEGMAX + lane];
  int sv1 = gsrc[n*DEGMAX + 64 + lane];
  const int deg = __builtin_amdgcn_readfirstlane(gdeg[n]);  // SGPR loop bound
  const int degm1 = deg - 1;

  // raw att / xr loads issue early; unpack is deferred below the prologue so
  // the VALU work rides under the edge-gather latency
  const f32x2* pa2 = (const f32x2*)(att + du*2);
  f32x2 ar[6];
  #pragma unroll
  for (int t=0;t<6;t++) ar[t] = pa2[t];
  const unsigned* px = (const unsigned*)(xr + ((size_t)b*NN + n)*DD) + du;
  u32x4 x0 = __builtin_nontemporal_load((const u32x4*)px);
  u32x2 x1 = __builtin_nontemporal_load((const u32x2*)(px+4));

  const unsigned short* xlb = xl + (size_t)b*NN*DD;

  // ---- prologue: 8 edges in flight (16 vmem), clamped beyond deg ----
  unsigned bA[6], bB[6], bC[6], bD[6], bE[6], bF[6], bG[6], bH[6];
  LOAD6(bA, EADDR(0));
  LOAD6(bB, EADDRC(1));
  LOAD6(bC, EADDRC(2));
  LOAD6(bD, EADDRC(3));
  LOAD6(bE, EADDRC(4));
  LOAD6(bF, EADDRC(5));
  LOAD6(bG, EADDRC(6));
  LOAD6(bH, EADDRC(7));

  // unpack att / xr (overlaps gather latency)
  h2 atth[6], xrh[6];
  const h2 c02h = {(_Float16)0.2f, (_Float16)0.2f};
#ifndef HAS_FDOT2
  float attf[12];
#endif
  #pragma unroll
  for (int t=0;t<6;t++){
    atth[t][0] = (_Float16)(ar[t].x * 1.4426950408889634f);  // fold log2e
    atth[t][1] = (_Float16)(ar[t].y * 1.4426950408889634f);
#ifndef HAS_FDOT2
    attf[2*t]   = ar[t].x * 1.4426950408889634f;
    attf[2*t+1] = ar[t].y * 1.4426950408889634f;
#endif
  }
  {
    unsigned xx[6] = {x0.x, x0.y, x0.z, x0.w, x1.x, x1.y};
    #pragma unroll
    for (int t=0;t<6;t++) xrh[t] = u2h(xx[t]);
  }
  f32x2 acc2[6];
  #pragma unroll
  for (int t=0;t<6;t++){ acc2[t].x = 0.f; acc2[t].y = 0.f; }

  float ssum = 0.f;
  const float C2 = 11.5415603f;      // 8*log2(e); softmax is shift-invariant

  // ---- main loop: 8 edges per iter; reloads issued 3 STEP2s before use ----
  int i = 0;
  for (; i + 8 <= deg; ){
    const bool more = (i + 8 < deg);       // uniform
    STEP2(bA, bB);
    if (more){ LOAD6(bA, EADDRC(i+8));  LOAD6(bB, EADDRC(i+9));  }
    STEP2(bC, bD);
    if (more){ LOAD6(bC, EADDRC(i+10)); LOAD6(bD, EADDRC(i+11)); }
    STEP2(bE, bF);
    if (more){ LOAD6(bE, EADDRC(i+12)); LOAD6(bF, EADDRC(i+13)); }
    STEP2(bG, bH);
    if (more){ LOAD6(bG, EADDRC(i+14)); LOAD6(bH, EADDRC(i+15)); }
    i += 8;
  }
  // ---- tail: rem in [0,7], all data already in registers/in flight ----
  {
    const int rem = deg - i;
    if (rem >= 2){ STEP2(bA, bB); } else if (rem == 1){ STEP1(bA); }
    if (rem >= 4){ STEP2(bC, bD); } else if (rem == 3){ STEP1(bC); }
    if (rem >= 6){ STEP2(bE, bF); } else if (rem == 5){ STEP1(bE); }
    if (rem == 7){ STEP1(bG); }
  }

  // out = acc_h/ssum - xr + bias   (since sum p*xr = ssum*xr); nt stores
  const float inv = 1.f / ssum;
  float* po = out + ((size_t)b*NN + n)*DD + du*2;
  const f32x2* pb2 = (const f32x2*)(bias + du*2);
  #pragma unroll
  for (int t=0;t<6;t+=2){
    f32x2 oa, ob;
    oa.x = acc2[t].x   * inv + (pb2[t].x   - (float)xrh[t][0]);
    oa.y = acc2[t].y   * inv + (pb2[t].y   - (float)xrh[t][1]);
    ob.x = acc2[t+1].x * inv + (pb2[t+1].x - (float)xrh[t+1][0]);
    ob.y = acc2[t+1].y * inv + (pb2[t+1].y - (float)xrh[t+1][1]);
    f32x4 o4; o4[0]=oa.x; o4[1]=oa.y; o4[2]=ob.x; o4[3]=ob.y;
    __builtin_nontemporal_store(o4, (f32x4*)(po + 2*t));
  }
}

extern "C" void kernel_launch(void* const* d_in, const int* in_sizes, int n_in,
                              void* d_out, int out_size, void* d_ws, size_t ws_size,
                              hipStream_t stream)
{
  const float* z   = (const float*)d_in[1];
  const int*   r1  = (const int*)  d_in[2];
  const int*   r2  = (const int*)  d_in[3];
  const float* Wl  = (const float*)d_in[4];
  const float* bl  = (const float*)d_in[5];
  const float* Wr  = (const float*)d_in[6];
  const float* br  = (const float*)d_in[7];
  const float* att = (const float*)d_in[8];
  const float* bias= (const float*)d_in[9];
  float* out = (float*)d_out;

  char* ws = (char*)d_ws;
  unsigned short* xl = (unsigned short*)(ws + XL_OFF);
  unsigned short* xr = (unsigned short*)(ws + XR_OFF);
  int* gsrc = (int*)(ws + GSRC_OFF);
  int* gdeg = (int*)(ws + GDEG_OFF);

  k_gemm<<<dim3(MM/64, DD/128, 2), 256, 0, stream>>>(z, Wl, bl, Wr, br,
                                                     r1, r2, gdeg, gsrc, xl, xr);
  k_fusedf<<<dim3(BB, (NN+3)/4), 256, 0, stream>>>(xl, xr, gdeg, gsrc, att, bias, out);
}

// Round 5
// 66.777 us; speedup vs baseline: 1.1306x; 1.0274x over previous
//
#include <hip/hip_runtime.h>

#define BB 64
#define NN 307
#define HH 64
#define DD 768
#define EE 2456
#define ET 2763           // EE + NN self loops
#define MM (BB*NN)        // 19648
#define DEGMAX 128
#define SEGCAP 48

// ---- ws layout (bytes) ----
#define XL_OFF   0u
#define XL_SZ    (MM*DD*2u)              // 30,179,328
#define XR_OFF   (XL_OFF + XL_SZ)
#define GSRC_OFF (XR_OFF + XL_SZ)        // [NN][DEGMAX] ints
#define GDEG_OFF (GSRC_OFF + NN*DEGMAX*4u)

typedef __attribute__((ext_vector_type(8))) _Float16 half8;
typedef __attribute__((ext_vector_type(2))) _Float16 h2;
typedef __attribute__((ext_vector_type(4))) float f32x4;
typedef __attribute__((ext_vector_type(2))) float f32x2;
typedef __attribute__((ext_vector_type(4))) unsigned u32x4;
typedef __attribute__((ext_vector_type(2))) unsigned u32x2;

#if defined(__has_builtin)
#if __has_builtin(__builtin_amdgcn_fdot2)
#define HAS_FDOT2 1
#endif
#endif

__device__ __forceinline__ unsigned short f2h(float f){
  union{_Float16 h; unsigned short u;} c; c.h = (_Float16)f; return c.u;
}
__device__ __forceinline__ h2 u2h(unsigned u){
  union{unsigned u; h2 h;} c; c.u = u; return c.h;
}

// ---------- 1. fused MFMA f16 GEMM (xl AND xr) + CSR, one dispatch -------
// grid (307, 6, 2): z=0 -> both GEMMs for tile (x,y); z=1 (y==0) -> CSR node x.
// (unchanged from round 3/4)
__global__ __launch_bounds__(256) void k_gemm(
    const float* __restrict__ z,
    const float* __restrict__ Wl, const float* __restrict__ bl,
    const float* __restrict__ Wr, const float* __restrict__ br,
    const int* __restrict__ r1, const int* __restrict__ r2,
    int* __restrict__ gdeg, int* __restrict__ gsrc,
    unsigned short* __restrict__ xl, unsigned short* __restrict__ xr)
{
  __shared__ unsigned short sBTl[128][72];  // Wl^T [col][k], padded (18 KB)
  __shared__ unsigned short sBTr[128][72];  // Wr^T [col][k], padded (18 KB)
  __shared__ unsigned short sC[64][136];    // epilogue staging, padded (17 KB)
  __shared__ int sseg[4][SEGCAP];
  __shared__ int scnt[4];

  const int tid = threadIdx.x;
  const int lane = tid & 63, wv = tid >> 6;

  if (blockIdx.z == 1){
    // ---- CSR: 4-wave segmented ballot scan for node n = blockIdx.x ----
    if (blockIdx.y != 0) return;
    const int n = blockIdx.x;
    const int W = (ET + 3) / 4;                 // 691
    const int e0 = wv * W;
    const int e1 = (e0 + W < ET) ? e0 + W : ET;
    int cnt = 0;
    for (int base = e0; base < e1; base += 64){
      int e = base + lane;
      int d = -1, s = 0;
      if (e < e1){
        if (e < EE){ d = r2[e]; s = r1[e]; }
        else       { d = e - EE; s = d; }
      }
      bool hit = (d == n);
      unsigned long long mb = __ballot(hit);
      if (hit){
        int pos = cnt + (int)__popcll(mb & ((1ull << lane) - 1ull));
        if (pos < SEGCAP) sseg[wv][pos] = s;
      }
      cnt += (int)__popcll(mb);
    }
    if (lane == 0) scnt[wv] = (cnt < SEGCAP) ? cnt : SEGCAP;
    __syncthreads();
    int c0 = scnt[0], c1 = scnt[1], c2 = scnt[2], c3 = scnt[3];
    int off = (wv > 0 ? c0 : 0) + (wv > 1 ? c1 : 0) + (wv > 2 ? c2 : 0);
    int cw = scnt[wv];
    int deg = c0 + c1 + c2 + c3;
    if (lane < cw && off + lane < DEGMAX) gsrc[n*DEGMAX + off + lane] = sseg[wv][lane];
    if (tid == 0) gdeg[n] = (deg < DEGMAX) ? deg : DEGMAX;
    return;
  }

  const int m0 = blockIdx.x*64, n0 = blockIdx.y*128;

  // stage BOTH W^T tiles (f32 -> f16), coalesced
  #pragma unroll
  for (int it=0; it<32; it++){
    int idx = it*256 + tid;
    int k = idx >> 7, c = idx & 127;
    sBTl[c][k] = f2h(Wl[(size_t)k*DD + n0 + c]);
    sBTr[c][k] = f2h(Wr[(size_t)k*DD + n0 + c]);
  }

  // shared A fragments (one z read serves both GEMMs)
  const int arow = m0 + wv*16 + (lane & 15);
  const int kp   = (lane >> 4) * 8;
  const float* pz = z + (size_t)arow*HH + kp;
  float4 za0 = *(const float4*)(pz);
  float4 za1 = *(const float4*)(pz + 4);
  float4 zb0 = *(const float4*)(pz + 32);
  float4 zb1 = *(const float4*)(pz + 36);
  half8 a0, a1;
  a0[0]=(_Float16)za0.x; a0[1]=(_Float16)za0.y; a0[2]=(_Float16)za0.z; a0[3]=(_Float16)za0.w;
  a0[4]=(_Float16)za1.x; a0[5]=(_Float16)za1.y; a0[6]=(_Float16)za1.z; a0[7]=(_Float16)za1.w;
  a1[0]=(_Float16)zb0.x; a1[1]=(_Float16)zb0.y; a1[2]=(_Float16)zb0.z; a1[3]=(_Float16)zb0.w;
  a1[4]=(_Float16)zb1.x; a1[5]=(_Float16)zb1.y; a1[6]=(_Float16)zb1.z; a1[7]=(_Float16)zb1.w;
  __syncthreads();

  const int bcol = lane & 15;
  f32x4 accl[8], accr[8];
  #pragma unroll
  for (int cb=0; cb<8; cb++){
    accl[cb][0]=0.f; accl[cb][1]=0.f; accl[cb][2]=0.f; accl[cb][3]=0.f;
    accr[cb][0]=0.f; accr[cb][1]=0.f; accr[cb][2]=0.f; accr[cb][3]=0.f;
  }

  #pragma unroll
  for (int cb=0; cb<8; cb++){
    half8 b0l = *(const half8*)&sBTl[cb*16 + bcol][kp];
    half8 b1l = *(const half8*)&sBTl[cb*16 + bcol][32 + kp];
    accl[cb] = __builtin_amdgcn_mfma_f32_16x16x32_f16(a0, b0l, accl[cb], 0, 0, 0);
    accl[cb] = __builtin_amdgcn_mfma_f32_16x16x32_f16(a1, b1l, accl[cb], 0, 0, 0);
    half8 b0r = *(const half8*)&sBTr[cb*16 + bcol][kp];
    half8 b1r = *(const half8*)&sBTr[cb*16 + bcol][32 + kp];
    accr[cb] = __builtin_amdgcn_mfma_f32_16x16x32_f16(a0, b0r, accr[cb], 0, 0, 0);
    accr[cb] = __builtin_amdgcn_mfma_f32_16x16x32_f16(a1, b1r, accr[cb], 0, 0, 0);
  }

  // epilogue xl
  #pragma unroll
  for (int cb=0; cb<8; cb++){
    int cc = cb*16 + bcol;
    float bb = bl[n0 + cc];
    #pragma unroll
    for (int r=0; r<4; r++){
      int rr = wv*16 + (lane>>4)*4 + r;
      sC[rr][cc] = f2h(accl[cb][r] + bb);
    }
  }
  __syncthreads();
  #pragma unroll
  for (int it=0; it<4; it++){
    int idx = it*256 + tid;
    int rr = idx >> 4;
    int c8 = (idx & 15) * 8;
    uint4 v = *(const uint4*)&sC[rr][c8];
    *(uint4*)&xl[(size_t)(m0+rr)*DD + n0 + c8] = v;
  }
  __syncthreads();
  // epilogue xr
  #pragma unroll
  for (int cb=0; cb<8; cb++){
    int cc = cb*16 + bcol;
    float bb = br[n0 + cc];
    #pragma unroll
    for (int r=0; r<4; r++){
      int rr = wv*16 + (lane>>4)*4 + r;
      sC[rr][cc] = f2h(accr[cb][r] + bb);
    }
  }
  __syncthreads();
  #pragma unroll
  for (int it=0; it<4; it++){
    int idx = it*256 + tid;
    int rr = idx >> 4;
    int c8 = (idx & 15) * 8;
    uint4 v = *(const uint4*)&sC[rr][c8];
    *(uint4*)&xr[(size_t)(m0+rr)*DD + n0 + c8] = v;
  }
}

// ---------- 2. fused score + fixed-shift-softmax + aggregation ------------
// grid (64, 77); 256 threads = 4 INDEPENDENT waves (no LDS/barriers).
// Round-5 change: CONTIGUOUS lane partition of each 1536 B row.
//   Old: lane owned bytes [lane*24, lane*24+24) -> dwordx4 @ stride 24 touches
//   all 24 lines of the row, and the dwordx2 touches them AGAIN (~44 line-
//   passes/edge at ~2.7 lanes served per pass) -> per-CU TA/L1 line pipe was
//   the invariant ~46-52us bottleneck across 5 kernel versions.
//   New: lane owns [lane*16,+16) (dwordx4, 1024B contiguous, 16 lines, one
//   pass) + [1024+lane*8,+8) (dwordx2, 512B, 8 lines). 24 line-passes/edge,
//   4 lanes/line. Score is a sum over any lane-partition of d, so only the
//   att/xr/bias/out index maps change. Everything else = round-4 verbatim.

template<int CTRL, int RM>
__device__ __forceinline__ float dpp_add(float v){
  int x = __builtin_amdgcn_update_dpp(0, __float_as_int(v), CTRL, RM, 0xf, true);
  return v + __int_as_float(x);
}
// 64-lane sum -> wave-uniform float (readlane 63). All-VALU, no LDS pipe.
__device__ __forceinline__ float redux64s(float v){
  v = dpp_add<0x121,0xf>(v);   // row_ror:1
  v = dpp_add<0x122,0xf>(v);   // row_ror:2
  v = dpp_add<0x124,0xf>(v);   // row_ror:4
  v = dpp_add<0x128,0xf>(v);   // row_ror:8   -> every lane: own 16-row sum
  v = dpp_add<0x142,0xa>(v);   // row_bcast:15 -> row1 += r0, row3 += r2
  v = dpp_add<0x143,0x8>(v);   // row_bcast:31 -> row3 += (r0+r1)
  return __uint_as_float((unsigned)__builtin_amdgcn_readlane(__float_as_int(v), 63));
}

// P is the row base (const unsigned*); duA/duB are the lane's two offsets
#define LOAD6(DST, P) {                                           \
  u32x4 _u0 = *(const u32x4*)((P) + duA);                         \
  u32x2 _u1 = *(const u32x2*)((P) + duB);                         \
  DST[0]=_u0.x; DST[1]=_u0.y; DST[2]=_u0.z; DST[3]=_u0.w;         \
  DST[4]=_u1.x; DST[5]=_u1.y; }

// scalar src id (J uniform) -> saddr row base; C-variant clamps to degm1
#define READS(J) __builtin_amdgcn_readlane((((J) & 64) ? sv1 : sv0), (J) & 63)
#define EADDR(J)  ((const unsigned*)(xlb + (size_t)READS(J)*DD))
#define EADDRC(J) ({ int _q = (J); int _qc = _q < degm1 ? _q : degm1;  \
                     (const unsigned*)(xlb + (size_t)READS(_qc)*DD); })

#define MKH(H, U) {                                               \
  _Pragma("unroll")                                               \
  for (int _t=0;_t<6;_t++) H[_t] = u2h(U[_t]) + xrh[_t]; }        // v_pk_add_f16

#ifdef HAS_FDOT2
#define SCORE(S, H) {                                             \
  _Pragma("unroll")                                               \
  for (int _t=0;_t<6;_t++){                                       \
    h2 _l = __builtin_elementwise_max(H[_t], H[_t]*c02h);         \
    S = __builtin_amdgcn_fdot2(_l, atth[_t], S, false); } }
#else
#define SCORE(S, H) {                                             \
  _Pragma("unroll")                                               \
  for (int _t=0;_t<6;_t++){                                       \
    h2 _l = __builtin_elementwise_max(H[_t], H[_t]*c02h);         \
    S += (float)_l[0]*attf[2*_t] + (float)_l[1]*attf[2*_t+1]; } }
#endif

#define ACCH(P, H) {                                              \
  _Pragma("unroll")                                               \
  for (int _t=0;_t<6;_t++){                                       \
    acc2[_t].x += (P) * (float)H[_t][0];                          \
    acc2[_t].y += (P) * (float)H[_t][1]; } }

#define STEP2(U, V) {                                             \
  h2 hU[6], hV[6];                                                \
  MKH(hU, U); MKH(hV, V);                                         \
  float sU = 0.f, sV = 0.f;                                       \
  SCORE(sU, hU); SCORE(sV, hV);                                   \
  float scU = redux64s(sU);                                       \
  float scV = redux64s(sV);                                       \
  float pU = __builtin_amdgcn_exp2f(scU - C2);                    \
  float pV = __builtin_amdgcn_exp2f(scV - C2);                    \
  ssum += pU + pV;                                                \
  ACCH(pU, hU); ACCH(pV, hV); }

#define STEP1(U) {                                                \
  h2 hU[6];                                                       \
  MKH(hU, U);                                                     \
  float sU = 0.f;                                                 \
  SCORE(sU, hU);                                                  \
  float scU = redux64s(sU);                                       \
  float pU = __builtin_amdgcn_exp2f(scU - C2);                    \
  ssum += pU;                                                     \
  ACCH(pU, hU); }

__global__ __launch_bounds__(256) void k_fusedf(
    const unsigned short* __restrict__ xl, const unsigned short* __restrict__ xr,
    const int* __restrict__ gdeg, const int* __restrict__ gsrc,
    const float* __restrict__ att, const float* __restrict__ bias,
    float* __restrict__ out)
{
  const int b = blockIdx.x;
  const int wv = threadIdx.x >> 6;
  const int nv = blockIdx.y*4 + wv;
  if (nv >= NN) return;                    // no barriers/LDS -> safe
  const int n = __builtin_amdgcn_readfirstlane(nv);  // wave-uniform -> SGPR
  const int lane = threadIdx.x & 63;
  // contiguous lane partition of the 384-uint row:
  //   slots 0..3: uints [lane*4, lane*4+4)    = d [lane*8, lane*8+8)
  //   slots 4..5: uints [256+lane*2, +2)      = d [512+lane*4, +4)
  const int duA = lane * 4;
  const int duB = 256 + lane * 2;

  // src list -> 2 VGPRs (coalesced); per-edge broadcast via v_readlane
  int sv0 = gsrc[n*DEGMAX + lane];
  int sv1 = gsrc[n*DEGMAX + 64 + lane];
  const int deg = __builtin_amdgcn_readfirstlane(gdeg[n]);  // SGPR loop bound
  const int degm1 = deg - 1;

  // raw att / xr loads issue early; unpack deferred below the prologue
  f32x2 ar[6];
  {
    const f32x2* paA = (const f32x2*)(att) + lane*4;        // 8 f32
    const f32x2* paB = (const f32x2*)(att + 512) + lane*2;  // 4 f32
    #pragma unroll
    for (int t=0;t<4;t++) ar[t] = paA[t];
    #pragma unroll
    for (int t=0;t<2;t++) ar[4+t] = paB[t];
  }
  const unsigned* px = (const unsigned*)(xr + ((size_t)b*NN + n)*DD);
  u32x4 x0 = __builtin_nontemporal_load((const u32x4*)(px + duA));
  u32x2 x1 = __builtin_nontemporal_load((const u32x2*)(px + duB));

  const unsigned short* xlb = xl + (size_t)b*NN*DD;

  // ---- prologue: 8 edges in flight (16 vmem), clamped beyond deg ----
  unsigned bA[6], bB[6], bC[6], bD[6], bE[6], bF[6], bG[6], bH[6];
  LOAD6(bA, EADDR(0));
  LOAD6(bB, EADDRC(1));
  LOAD6(bC, EADDRC(2));
  LOAD6(bD, EADDRC(3));
  LOAD6(bE, EADDRC(4));
  LOAD6(bF, EADDRC(5));
  LOAD6(bG, EADDRC(6));
  LOAD6(bH, EADDRC(7));

  // unpack att / xr (overlaps gather latency)
  h2 atth[6], xrh[6];
  const h2 c02h = {(_Float16)0.2f, (_Float16)0.2f};
#ifndef HAS_FDOT2
  float attf[12];
#endif
  #pragma unroll
  for (int t=0;t<6;t++){
    atth[t][0] = (_Float16)(ar[t].x * 1.4426950408889634f);  // fold log2e
    atth[t][1] = (_Float16)(ar[t].y * 1.4426950408889634f);
#ifndef HAS_FDOT2
    attf[2*t]   = ar[t].x * 1.4426950408889634f;
    attf[2*t+1] = ar[t].y * 1.4426950408889634f;
#endif
  }
  {
    unsigned xx[6] = {x0.x, x0.y, x0.z, x0.w, x1.x, x1.y};
    #pragma unroll
    for (int t=0;t<6;t++) xrh[t] = u2h(xx[t]);
  }
  f32x2 acc2[6];
  #pragma unroll
  for (int t=0;t<6;t++){ acc2[t].x = 0.f; acc2[t].y = 0.f; }

  float ssum = 0.f;
  const float C2 = 11.5415603f;      // 8*log2(e); softmax is shift-invariant

  // ---- main loop: 8 edges per iter; reloads issued 3 STEP2s before use ----
  int i = 0;
  for (; i + 8 <= deg; ){
    const bool more = (i + 8 < deg);       // uniform
    STEP2(bA, bB);
    if (more){ LOAD6(bA, EADDRC(i+8));  LOAD6(bB, EADDRC(i+9));  }
    STEP2(bC, bD);
    if (more){ LOAD6(bC, EADDRC(i+10)); LOAD6(bD, EADDRC(i+11)); }
    STEP2(bE, bF);
    if (more){ LOAD6(bE, EADDRC(i+12)); LOAD6(bF, EADDRC(i+13)); }
    STEP2(bG, bH);
    if (more){ LOAD6(bG, EADDRC(i+14)); LOAD6(bH, EADDRC(i+15)); }
    i += 8;
  }
  // ---- tail: rem in [0,7], all data already in registers/in flight ----
  {
    const int rem = deg - i;
    if (rem >= 2){ STEP2(bA, bB); } else if (rem == 1){ STEP1(bA); }
    if (rem >= 4){ STEP2(bC, bD); } else if (rem == 3){ STEP1(bC); }
    if (rem >= 6){ STEP2(bE, bF); } else if (rem == 5){ STEP1(bE); }
    if (rem == 7){ STEP1(bG); }
  }

  // out = acc_h/ssum - xr + bias   (since sum p*xr = ssum*xr); nt stores
  const float inv = 1.f / ssum;
  float* po = out + ((size_t)b*NN + n)*DD;
  const f32x2* pbA = (const f32x2*)(bias) + lane*4;
  const f32x2* pbB = (const f32x2*)(bias + 512) + lane*2;
  f32x2 pb[6];
  #pragma unroll
  for (int t=0;t<4;t++) pb[t] = pbA[t];
  #pragma unroll
  for (int t=0;t<2;t++) pb[4+t] = pbB[t];

  f32x2 o2[6];
  #pragma unroll
  for (int t=0;t<6;t++){
    o2[t].x = acc2[t].x * inv + (pb[t].x - (float)xrh[t][0]);
    o2[t].y = acc2[t].y * inv + (pb[t].y - (float)xrh[t][1]);
  }
  {
    f32x4 oa; oa[0]=o2[0].x; oa[1]=o2[0].y; oa[2]=o2[1].x; oa[3]=o2[1].y;
    f32x4 ob; ob[0]=o2[2].x; ob[1]=o2[2].y; ob[2]=o2[3].x; ob[3]=o2[3].y;
    f32x4 oc; oc[0]=o2[4].x; oc[1]=o2[4].y; oc[2]=o2[5].x; oc[3]=o2[5].y;
    __builtin_nontemporal_store(oa, (f32x4*)(po + lane*8));
    __builtin_nontemporal_store(ob, (f32x4*)(po + lane*8 + 4));
    __builtin_nontemporal_store(oc, (f32x4*)(po + 512 + lane*4));
  }
}

extern "C" void kernel_launch(void* const* d_in, const int* in_sizes, int n_in,
                              void* d_out, int out_size, void* d_ws, size_t ws_size,
                              hipStream_t stream)
{
  const float* z   = (const float*)d_in[1];
  const int*   r1  = (const int*)  d_in[2];
  const int*   r2  = (const int*)  d_in[3];
  const float* Wl  = (const float*)d_in[4];
  const float* bl  = (const float*)d_in[5];
  const float* Wr  = (const float*)d_in[6];
  const float* br  = (const float*)d_in[7];
  const float* att = (const float*)d_in[8];
  const float* bias= (const float*)d_in[9];
  float* out = (float*)d_out;

  char* ws = (char*)d_ws;
  unsigned short* xl = (unsigned short*)(ws + XL_OFF);
  unsigned short* xr = (unsigned short*)(ws + XR_OFF);
  int* gsrc = (int*)(ws + GSRC_OFF);
  int* gdeg = (int*)(ws + GDEG_OFF);

  k_gemm<<<dim3(MM/64, DD/128, 2), 256, 0, stream>>>(z, Wl, bl, Wr, br,
                                                     r1, r2, gdeg, gsrc, xl, xr);
  k_fusedf<<<dim3(BB, (NN+3)/4), 256, 0, stream>>>(xl, xr, gdeg, gsrc, att, bias, out);
}

// Round 6
// 63.436 us; speedup vs baseline: 1.1902x; 1.0527x over previous
//
#include <hip/hip_runtime.h>

#define BB 64
#define NN 307
#define HH 64
#define DD 768
#define EE 2456
#define ET 2763           // EE + NN self loops
#define MM (BB*NN)        // 19648
#define DEGMAX 128
#define SEGCAP 48
#define NG 77             // node groups of 4 (307 -> 77)

// ---- ws layout (bytes) ----
#define XL_OFF   0u
#define XL_SZ    (MM*DD*2u)              // 30,179,328
#define XR_OFF   (XL_OFF + XL_SZ)
#define GSRC_OFF (XR_OFF + XL_SZ)        // [NN][DEGMAX] ints
#define GDEG_OFF (GSRC_OFF + NN*DEGMAX*4u)

typedef __attribute__((ext_vector_type(8))) _Float16 half8;
typedef __attribute__((ext_vector_type(2))) _Float16 h2;
typedef __attribute__((ext_vector_type(4))) float f32x4;
typedef __attribute__((ext_vector_type(2))) float f32x2;
typedef __attribute__((ext_vector_type(4))) unsigned u32x4;
typedef __attribute__((ext_vector_type(2))) unsigned u32x2;

#if defined(__has_builtin)
#if __has_builtin(__builtin_amdgcn_fdot2)
#define HAS_FDOT2 1
#endif
#endif

__device__ __forceinline__ unsigned short f2h(float f){
  union{_Float16 h; unsigned short u;} c; c.h = (_Float16)f; return c.u;
}
__device__ __forceinline__ h2 u2h(unsigned u){
  union{unsigned u; h2 h;} c; c.u = u; return c.h;
}

// ---------- 1. fused MFMA f16 GEMM (xl AND xr) + CSR, one dispatch -------
// grid (307, 6, 2): z=0 -> both GEMMs for tile (x,y); z=1 (y==0) -> CSR node x.
// (unchanged from rounds 3-5)
__global__ __launch_bounds__(256) void k_gemm(
    const float* __restrict__ z,
    const float* __restrict__ Wl, const float* __restrict__ bl,
    const float* __restrict__ Wr, const float* __restrict__ br,
    const int* __restrict__ r1, const int* __restrict__ r2,
    int* __restrict__ gdeg, int* __restrict__ gsrc,
    unsigned short* __restrict__ xl, unsigned short* __restrict__ xr)
{
  __shared__ unsigned short sBTl[128][72];  // Wl^T [col][k], padded (18 KB)
  __shared__ unsigned short sBTr[128][72];  // Wr^T [col][k], padded (18 KB)
  __shared__ unsigned short sC[64][136];    // epilogue staging, padded (17 KB)
  __shared__ int sseg[4][SEGCAP];
  __shared__ int scnt[4];

  const int tid = threadIdx.x;
  const int lane = tid & 63, wv = tid >> 6;

  if (blockIdx.z == 1){
    // ---- CSR: 4-wave segmented ballot scan for node n = blockIdx.x ----
    if (blockIdx.y != 0) return;
    const int n = blockIdx.x;
    const int W = (ET + 3) / 4;                 // 691
    const int e0 = wv * W;
    const int e1 = (e0 + W < ET) ? e0 + W : ET;
    int cnt = 0;
    for (int base = e0; base < e1; base += 64){
      int e = base + lane;
      int d = -1, s = 0;
      if (e < e1){
        if (e < EE){ d = r2[e]; s = r1[e]; }
        else       { d = e - EE; s = d; }
      }
      bool hit = (d == n);
      unsigned long long mb = __ballot(hit);
      if (hit){
        int pos = cnt + (int)__popcll(mb & ((1ull << lane) - 1ull));
        if (pos < SEGCAP) sseg[wv][pos] = s;
      }
      cnt += (int)__popcll(mb);
    }
    if (lane == 0) scnt[wv] = (cnt < SEGCAP) ? cnt : SEGCAP;
    __syncthreads();
    int c0 = scnt[0], c1 = scnt[1], c2 = scnt[2], c3 = scnt[3];
    int off = (wv > 0 ? c0 : 0) + (wv > 1 ? c1 : 0) + (wv > 2 ? c2 : 0);
    int cw = scnt[wv];
    int deg = c0 + c1 + c2 + c3;
    if (lane < cw && off + lane < DEGMAX) gsrc[n*DEGMAX + off + lane] = sseg[wv][lane];
    if (tid == 0) gdeg[n] = (deg < DEGMAX) ? deg : DEGMAX;
    return;
  }

  const int m0 = blockIdx.x*64, n0 = blockIdx.y*128;

  // stage BOTH W^T tiles (f32 -> f16), coalesced
  #pragma unroll
  for (int it=0; it<32; it++){
    int idx = it*256 + tid;
    int k = idx >> 7, c = idx & 127;
    sBTl[c][k] = f2h(Wl[(size_t)k*DD + n0 + c]);
    sBTr[c][k] = f2h(Wr[(size_t)k*DD + n0 + c]);
  }

  // shared A fragments (one z read serves both GEMMs)
  const int arow = m0 + wv*16 + (lane & 15);
  const int kp   = (lane >> 4) * 8;
  const float* pz = z + (size_t)arow*HH + kp;
  float4 za0 = *(const float4*)(pz);
  float4 za1 = *(const float4*)(pz + 4);
  float4 zb0 = *(const float4*)(pz + 32);
  float4 zb1 = *(const float4*)(pz + 36);
  half8 a0, a1;
  a0[0]=(_Float16)za0.x; a0[1]=(_Float16)za0.y; a0[2]=(_Float16)za0.z; a0[3]=(_Float16)za0.w;
  a0[4]=(_Float16)za1.x; a0[5]=(_Float16)za1.y; a0[6]=(_Float16)za1.z; a0[7]=(_Float16)za1.w;
  a1[0]=(_Float16)zb0.x; a1[1]=(_Float16)zb0.y; a1[2]=(_Float16)zb0.z; a1[3]=(_Float16)zb0.w;
  a1[4]=(_Float16)zb1.x; a1[5]=(_Float16)zb1.y; a1[6]=(_Float16)zb1.z; a1[7]=(_Float16)zb1.w;
  __syncthreads();

  const int bcol = lane & 15;
  f32x4 accl[8], accr[8];
  #pragma unroll
  for (int cb=0; cb<8; cb++){
    accl[cb][0]=0.f; accl[cb][1]=0.f; accl[cb][2]=0.f; accl[cb][3]=0.f;
    accr[cb][0]=0.f; accr[cb][1]=0.f; accr[cb][2]=0.f; accr[cb][3]=0.f;
  }

  #pragma unroll
  for (int cb=0; cb<8; cb++){
    half8 b0l = *(const half8*)&sBTl[cb*16 + bcol][kp];
    half8 b1l = *(const half8*)&sBTl[cb*16 + bcol][32 + kp];
    accl[cb] = __builtin_amdgcn_mfma_f32_16x16x32_f16(a0, b0l, accl[cb], 0, 0, 0);
    accl[cb] = __builtin_amdgcn_mfma_f32_16x16x32_f16(a1, b1l, accl[cb], 0, 0, 0);
    half8 b0r = *(const half8*)&sBTr[cb*16 + bcol][kp];
    half8 b1r = *(const half8*)&sBTr[cb*16 + bcol][32 + kp];
    accr[cb] = __builtin_amdgcn_mfma_f32_16x16x32_f16(a0, b0r, accr[cb], 0, 0, 0);
    accr[cb] = __builtin_amdgcn_mfma_f32_16x16x32_f16(a1, b1r, accr[cb], 0, 0, 0);
  }

  // epilogue xl
  #pragma unroll
  for (int cb=0; cb<8; cb++){
    int cc = cb*16 + bcol;
    float bb = bl[n0 + cc];
    #pragma unroll
    for (int r=0; r<4; r++){
      int rr = wv*16 + (lane>>4)*4 + r;
      sC[rr][cc] = f2h(accl[cb][r] + bb);
    }
  }
  __syncthreads();
  #pragma unroll
  for (int it=0; it<4; it++){
    int idx = it*256 + tid;
    int rr = idx >> 4;
    int c8 = (idx & 15) * 8;
    uint4 v = *(const uint4*)&sC[rr][c8];
    *(uint4*)&xl[(size_t)(m0+rr)*DD + n0 + c8] = v;
  }
  __syncthreads();
  // epilogue xr
  #pragma unroll
  for (int cb=0; cb<8; cb++){
    int cc = cb*16 + bcol;
    float bb = br[n0 + cc];
    #pragma unroll
    for (int r=0; r<4; r++){
      int rr = wv*16 + (lane>>4)*4 + r;
      sC[rr][cc] = f2h(accr[cb][r] + bb);
    }
  }
  __syncthreads();
  #pragma unroll
  for (int it=0; it<4; it++){
    int idx = it*256 + tid;
    int rr = idx >> 4;
    int c8 = (idx & 15) * 8;
    uint4 v = *(const uint4*)&sC[rr][c8];
    *(uint4*)&xr[(size_t)(m0+rr)*DD + n0 + c8] = v;
  }
}

// ---------- 2. fused score + fixed-shift-softmax + aggregation ------------
// Round-6 change: XCD-sequential batch mapping for L2 residency.
//   Old grid (64,77): blocks of ALL 64 b's interleave on every XCD ->
//   per-XCD xl working set 3.77 MB + xr/out streams thrash the 4 MB L2 ->
//   the 271 MB gather stream is served by the Infinity Cache at the per-XCD
//   L3 attach BW (~34 MB / XCD / ~0.75 TB/s ~= 45 us) -- the invariant
//   bottleneck across rounds 0-5 (duration immune to VALU/pipeline edits,
//   FETCH_SIZE 33 MB proves HBM saw each byte once).
//   New: 1-D grid, id%8 = XCD (dispatch round-robin), each XCD walks its 8
//   b-slices SEQUENTIALLY: b = (id&7) + 8*((id>>3)/77), g = (id>>3)%77.
//   Live working set per XCD = one xl[b]+xr[b] pair = 942 KB << 4 MB L2;
//   all ~9x re-reads L2-hit at 4.3 TB/s/XCD.
// Also: pipeline depth 8 -> 6 (12 vmem in flight is ample at L2 latency;
// frees ~12 VGPR). Math identical to rounds 3-5.

template<int CTRL, int RM>
__device__ __forceinline__ float dpp_add(float v){
  int x = __builtin_amdgcn_update_dpp(0, __float_as_int(v), CTRL, RM, 0xf, true);
  return v + __int_as_float(x);
}
// 64-lane sum -> wave-uniform float (readlane 63). All-VALU, no LDS pipe.
__device__ __forceinline__ float redux64s(float v){
  v = dpp_add<0x121,0xf>(v);   // row_ror:1
  v = dpp_add<0x122,0xf>(v);   // row_ror:2
  v = dpp_add<0x124,0xf>(v);   // row_ror:4
  v = dpp_add<0x128,0xf>(v);   // row_ror:8   -> every lane: own 16-row sum
  v = dpp_add<0x142,0xa>(v);   // row_bcast:15 -> row1 += r0, row3 += r2
  v = dpp_add<0x143,0x8>(v);   // row_bcast:31 -> row3 += (r0+r1)
  return __uint_as_float((unsigned)__builtin_amdgcn_readlane(__float_as_int(v), 63));
}

// P is the row base (const unsigned*); duA/duB are the lane's two offsets
#define LOAD6(DST, P) {                                           \
  u32x4 _u0 = *(const u32x4*)((P) + duA);                         \
  u32x2 _u1 = *(const u32x2*)((P) + duB);                         \
  DST[0]=_u0.x; DST[1]=_u0.y; DST[2]=_u0.z; DST[3]=_u0.w;         \
  DST[4]=_u1.x; DST[5]=_u1.y; }

// scalar src id (J uniform) -> saddr row base; C-variant clamps to degm1
#define READS(J) __builtin_amdgcn_readlane((((J) & 64) ? sv1 : sv0), (J) & 63)
#define EADDR(J)  ((const unsigned*)(xlb + (size_t)READS(J)*DD))
#define EADDRC(J) ({ int _q = (J); int _qc = _q < degm1 ? _q : degm1;  \
                     (const unsigned*)(xlb + (size_t)READS(_qc)*DD); })

#define MKH(H, U) {                                               \
  _Pragma("unroll")                                               \
  for (int _t=0;_t<6;_t++) H[_t] = u2h(U[_t]) + xrh[_t]; }        // v_pk_add_f16

#ifdef HAS_FDOT2
#define SCORE(S, H) {                                             \
  _Pragma("unroll")                                               \
  for (int _t=0;_t<6;_t++){                                       \
    h2 _l = __builtin_elementwise_max(H[_t], H[_t]*c02h);         \
    S = __builtin_amdgcn_fdot2(_l, atth[_t], S, false); } }
#else
#define SCORE(S, H) {                                             \
  _Pragma("unroll")                                               \
  for (int _t=0;_t<6;_t++){                                       \
    h2 _l = __builtin_elementwise_max(H[_t], H[_t]*c02h);         \
    S += (float)_l[0]*attf[2*_t] + (float)_l[1]*attf[2*_t+1]; } }
#endif

#define ACCH(P, H) {                                              \
  _Pragma("unroll")                                               \
  for (int _t=0;_t<6;_t++){                                       \
    acc2[_t].x += (P) * (float)H[_t][0];                          \
    acc2[_t].y += (P) * (float)H[_t][1]; } }

#define STEP2(U, V) {                                             \
  h2 hU[6], hV[6];                                                \
  MKH(hU, U); MKH(hV, V);                                         \
  float sU = 0.f, sV = 0.f;                                       \
  SCORE(sU, hU); SCORE(sV, hV);                                   \
  float scU = redux64s(sU);                                       \
  float scV = redux64s(sV);                                       \
  float pU = __builtin_amdgcn_exp2f(scU - C2);                    \
  float pV = __builtin_amdgcn_exp2f(scV - C2);                    \
  ssum += pU + pV;                                                \
  ACCH(pU, hU); ACCH(pV, hV); }

#define STEP1(U) {                                                \
  h2 hU[6];                                                       \
  MKH(hU, U);                                                     \
  float sU = 0.f;                                                 \
  SCORE(sU, hU);                                                  \
  float scU = redux64s(sU);                                       \
  float pU = __builtin_amdgcn_exp2f(scU - C2);                    \
  ssum += pU;                                                     \
  ACCH(pU, hU); }

__global__ __launch_bounds__(256) void k_fusedf(
    const unsigned short* __restrict__ xl, const unsigned short* __restrict__ xr,
    const int* __restrict__ gdeg, const int* __restrict__ gsrc,
    const float* __restrict__ att, const float* __restrict__ bias,
    float* __restrict__ out)
{
  // XCD-sequential batch mapping (1-D grid of 8*8*NG = 4928 blocks):
  //   id%8 -> XCD (round-robin dispatch); each XCD walks k = id>>3 in order,
  //   doing all NG node-groups of one b before moving to its next b.
  const unsigned id = blockIdx.x;
  const int xcd = (int)(id & 7u);
  const unsigned k = id >> 3;              // 0 .. 8*NG-1
  const int b = xcd + 8 * (int)(k / NG);
  const int g = (int)(k % NG);
  const int wv = threadIdx.x >> 6;
  const int nv = g*4 + wv;
  if (nv >= NN) return;                    // no barriers/LDS -> safe
  const int n = __builtin_amdgcn_readfirstlane(nv);  // wave-uniform -> SGPR
  const int lane = threadIdx.x & 63;
  // contiguous lane partition of the 384-uint row:
  //   slots 0..3: uints [lane*4, lane*4+4)    = d [lane*8, lane*8+8)
  //   slots 4..5: uints [256+lane*2, +2)      = d [512+lane*4, +4)
  const int duA = lane * 4;
  const int duB = 256 + lane * 2;

  // src list -> 2 VGPRs (coalesced); per-edge broadcast via v_readlane
  int sv0 = gsrc[n*DEGMAX + lane];
  int sv1 = gsrc[n*DEGMAX + 64 + lane];
  const int deg = __builtin_amdgcn_readfirstlane(gdeg[n]);  // SGPR loop bound
  const int degm1 = deg - 1;

  // raw att / xr loads issue early; unpack deferred below the prologue
  f32x2 ar[6];
  {
    const f32x2* paA = (const f32x2*)(att) + lane*4;        // 8 f32
    const f32x2* paB = (const f32x2*)(att + 512) + lane*2;  // 4 f32
    #pragma unroll
    for (int t=0;t<4;t++) ar[t] = paA[t];
    #pragma unroll
    for (int t=0;t<2;t++) ar[4+t] = paB[t];
  }
  const unsigned* px = (const unsigned*)(xr + ((size_t)b*NN + n)*DD);
  u32x4 x0 = __builtin_nontemporal_load((const u32x4*)(px + duA));
  u32x2 x1 = __builtin_nontemporal_load((const u32x2*)(px + duB));

  const unsigned short* xlb = xl + (size_t)b*NN*DD;

  // ---- prologue: 6 edges in flight (12 vmem), clamped beyond deg ----
  unsigned bA[6], bB[6], bC[6], bD[6], bE[6], bF[6];
  LOAD6(bA, EADDR(0));
  LOAD6(bB, EADDRC(1));
  LOAD6(bC, EADDRC(2));
  LOAD6(bD, EADDRC(3));
  LOAD6(bE, EADDRC(4));
  LOAD6(bF, EADDRC(5));

  // unpack att / xr (overlaps gather latency)
  h2 atth[6], xrh[6];
  const h2 c02h = {(_Float16)0.2f, (_Float16)0.2f};
#ifndef HAS_FDOT2
  float attf[12];
#endif
  #pragma unroll
  for (int t=0;t<6;t++){
    atth[t][0] = (_Float16)(ar[t].x * 1.4426950408889634f);  // fold log2e
    atth[t][1] = (_Float16)(ar[t].y * 1.4426950408889634f);
#ifndef HAS_FDOT2
    attf[2*t]   = ar[t].x * 1.4426950408889634f;
    attf[2*t+1] = ar[t].y * 1.4426950408889634f;
#endif
  }
  {
    unsigned xx[6] = {x0.x, x0.y, x0.z, x0.w, x1.x, x1.y};
    #pragma unroll
    for (int t=0;t<6;t++) xrh[t] = u2h(xx[t]);
  }
  f32x2 acc2[6];
  #pragma unroll
  for (int t=0;t<6;t++){ acc2[t].x = 0.f; acc2[t].y = 0.f; }

  float ssum = 0.f;
  const float C2 = 11.5415603f;      // 8*log2(e); softmax is shift-invariant

  // ---- main loop: 6 edges per iter; reloads issued ~3 STEP2s before use ----
  int i = 0;
  for (; i + 6 <= deg; ){
    const bool more = (i + 6 < deg);       // uniform
    STEP2(bA, bB);
    if (more){ LOAD6(bA, EADDRC(i+6));  LOAD6(bB, EADDRC(i+7));  }
    STEP2(bC, bD);
    if (more){ LOAD6(bC, EADDRC(i+8));  LOAD6(bD, EADDRC(i+9));  }
    STEP2(bE, bF);
    if (more){ LOAD6(bE, EADDRC(i+10)); LOAD6(bF, EADDRC(i+11)); }
    i += 6;
  }
  // ---- tail: rem in [0,5], all data already in registers ----
  {
    const int rem = deg - i;
    if (rem >= 2){ STEP2(bA, bB); } else if (rem == 1){ STEP1(bA); }
    if (rem >= 4){ STEP2(bC, bD); } else if (rem == 3){ STEP1(bC); }
    if (rem == 5){ STEP1(bE); }
  }

  // out = acc_h/ssum - xr + bias   (since sum p*xr = ssum*xr); nt stores
  const float inv = 1.f / ssum;
  float* po = out + ((size_t)b*NN + n)*DD;
  const f32x2* pbA = (const f32x2*)(bias) + lane*4;
  const f32x2* pbB = (const f32x2*)(bias + 512) + lane*2;
  f32x2 pb[6];
  #pragma unroll
  for (int t=0;t<4;t++) pb[t] = pbA[t];
  #pragma unroll
  for (int t=0;t<2;t++) pb[4+t] = pbB[t];

  f32x2 o2[6];
  #pragma unroll
  for (int t=0;t<6;t++){
    o2[t].x = acc2[t].x * inv + (pb[t].x - (float)xrh[t][0]);
    o2[t].y = acc2[t].y * inv + (pb[t].y - (float)xrh[t][1]);
  }
  {
    f32x4 oa; oa[0]=o2[0].x; oa[1]=o2[0].y; oa[2]=o2[1].x; oa[3]=o2[1].y;
    f32x4 ob; ob[0]=o2[2].x; ob[1]=o2[2].y; ob[2]=o2[3].x; ob[3]=o2[3].y;
    f32x4 oc; oc[0]=o2[4].x; oc[1]=o2[4].y; oc[2]=o2[5].x; oc[3]=o2[5].y;
    __builtin_nontemporal_store(oa, (f32x4*)(po + lane*8));
    __builtin_nontemporal_store(ob, (f32x4*)(po + lane*8 + 4));
    __builtin_nontemporal_store(oc, (f32x4*)(po + 512 + lane*4));
  }
}

extern "C" void kernel_launch(void* const* d_in, const int* in_sizes, int n_in,
                              void* d_out, int out_size, void* d_ws, size_t ws_size,
                              hipStream_t stream)
{
  const float* z   = (const float*)d_in[1];
  const int*   r1  = (const int*)  d_in[2];
  const int*   r2  = (const int*)  d_in[3];
  const float* Wl  = (const float*)d_in[4];
  const float* bl  = (const float*)d_in[5];
  const float* Wr  = (const float*)d_in[6];
  const float* br  = (const float*)d_in[7];
  const float* att = (const float*)d_in[8];
  const float* bias= (const float*)d_in[9];
  float* out = (float*)d_out;

  char* ws = (char*)d_ws;
  unsigned short* xl = (unsigned short*)(ws + XL_OFF);
  unsigned short* xr = (unsigned short*)(ws + XR_OFF);
  int* gsrc = (int*)(ws + GSRC_OFF);
  int* gdeg = (int*)(ws + GDEG_OFF);

  k_gemm<<<dim3(MM/64, DD/128, 2), 256, 0, stream>>>(z, Wl, bl, Wr, br,
                                                     r1, r2, gdeg, gsrc, xl, xr);
  k_fusedf<<<dim3(8*8*NG, 1, 1), 256, 0, stream>>>(xl, xr, gdeg, gsrc, att, bias, out);
}